// Round 5
// baseline (762.887 us; speedup 1.0000x reference)
//
#include <hip/hip_runtime.h>

#define VSZ 50257
#define DSZ 1024
#define TSZ 512
#define BSZ 4
#define HSZ 4096
#define VPAD 50432   // 197*256
#define NCH (VPAD / 64)   // 788 v-stripes of 64
#define NPOS 2048

typedef __attribute__((ext_vector_type(8))) __bf16 bf16x8;
typedef __attribute__((ext_vector_type(4))) float f32x4;

#define GLD16(gp, lp) __builtin_amdgcn_global_load_lds( \
  (const __attribute__((address_space(1))) unsigned int*)(gp), \
  (__attribute__((address_space(3))) unsigned int*)(lp), 16, 0, 0)

__device__ __forceinline__ float gelu_f(float x) {
  float x3 = x * x * x;
  float u = 0.7978845608028654f * (x + 0.044715f * x3);
  return 0.5f * x * (1.f + tanhf(u));
}

// -------- transpose + f32->bf16: src (R x C) -> dst (Cpad x R); 64x64 tiles
__global__ __launch_bounds__(256) void transpose_conv64(const float* __restrict__ src,
                                                        __bf16* __restrict__ dst,
                                                        int R, int C, int Cpad) {
  __shared__ float tile[64][65];
  int c0 = blockIdx.x * 64, r0 = blockIdx.y * 64;
  int tid = threadIdx.x;
  int wv = tid >> 6, ln = tid & 63;
  int c = c0 + ln;
#pragma unroll 4
  for (int i = 0; i < 16; ++i) {
    int r = i * 4 + wv;
    tile[r][ln] = (c < C) ? src[(size_t)(r0 + r) * C + c] : 0.f;
  }
  __syncthreads();
  int ccb = tid >> 4;          // 0..15, +j*16
  int r4 = (tid & 15) * 4;     // row quad
#pragma unroll
  for (int j = 0; j < 4; ++j) {
    int cc = ccb + j * 16;
    union { ushort4 u4; ushort s[4]; } pk;
#pragma unroll
    for (int q = 0; q < 4; ++q) {
      union { __bf16 b; ushort s; } cv;
      cv.b = (__bf16)tile[r4 + q][cc];
      pk.s[q] = cv.s;
    }
    *(ushort4*)(dst + (size_t)(c0 + cc) * R + r0 + r4) = pk.u4;
  }
}

// -------- encoder layer 1 partials: K-split dot over d-chunk of 128
#define KS1 8
__global__ __launch_bounds__(256) void enc1p_kernel(const int* __restrict__ ids,
                                                    const float* __restrict__ wte,
                                                    const float* __restrict__ w1,
                                                    float* __restrict__ t1p) {
  int b = blockIdx.x;
  int h = blockIdx.y * 256 + threadIdx.x;
  int kc = blockIdx.z;
  int tok = ids[b * TSZ + (TSZ - 1)];
  const float* ev = wte + (size_t)tok * DSZ + kc * (DSZ / KS1);
  const float* w = w1 + (size_t)kc * (DSZ / KS1) * HSZ + h;
  float s = 0.f;
#pragma unroll 4
  for (int d = 0; d < DSZ / KS1; ++d) s += ev[d] * w[(size_t)d * HSZ];
  t1p[((size_t)(b * KS1 + kc)) * HSZ + h] = s;
}

// -------- encoder layer 2 partials (enc1 combine + gelu fused in):
#define KS2 16
__global__ __launch_bounds__(256) void enc2p_kernel(const float* __restrict__ t1p,
                                                    const float* __restrict__ b1,
                                                    const float* __restrict__ w2,
                                                    float* __restrict__ ep) {
  __shared__ float ts[256];   // HSZ/KS2
  int b = blockIdx.x;
  int i = blockIdx.y * 256 + threadIdx.x;
  int kc = blockIdx.z;
  int h = kc * 256 + threadIdx.x;
  float s0 = b1[h];
#pragma unroll
  for (int cc = 0; cc < KS1; ++cc) s0 += t1p[((size_t)(b * KS1 + cc)) * HSZ + h];
  ts[threadIdx.x] = gelu_f(s0);
  __syncthreads();
  const float* w = w2 + (size_t)kc * 256 * DSZ + i;
  float s = 0.f;
#pragma unroll 4
  for (int j = 0; j < 256; ++j) s += ts[j] * w[(size_t)j * DSZ];
  ep[((size_t)(b * KS2 + kc)) * DSZ + i] = s;
}

__global__ __launch_bounds__(256) void enc2c_kernel(const float* __restrict__ ep,
                                                    const float* __restrict__ b2,
                                                    float* __restrict__ e) {
  int idx = blockIdx.x * 256 + threadIdx.x;   // b*DSZ + i
  int b = idx >> 10, i = idx & (DSZ - 1);
  float s = b2[i];
#pragma unroll
  for (int kc = 0; kc < KS2; ++kc) s += ep[((size_t)(b * KS2 + kc)) * DSZ + i];
  e[idx] = s;
}

// -------- windows: win[b*T+t][j] = bf16(e[b][t+j])   (t+j < 1024 always)
__global__ void win_kernel(const float* __restrict__ e, __bf16* __restrict__ win) {
  int blk = blockIdx.x;               // b*512 + t
  int b = blk >> 9, t = blk & 511;
  const float* eb = e + b * DSZ;
  for (int j = threadIdx.x; j < 512; j += 256)
    win[(size_t)blk * 512 + j] = (__bf16)eb[t + j];
}

// -------- GEMM (MODE 0 only): C[m][n] = sum_k A[m][k]*B[n][k], bf16 out + bias, opt gelu
template<int GELU>
__global__ __launch_bounds__(256) void gemm128(
    const __bf16* __restrict__ A, const __bf16* __restrict__ Bm,
    const float* __restrict__ bias, __bf16* __restrict__ outB,
    int NT, int M, int N, int K) {
  __shared__ __align__(16) char SM[16384];
  char* smA = SM;
  char* smB = SM + 8192;
  const int tid = threadIdx.x;
  const int lane = tid & 63;
  const int wave = tid >> 6;
  const int wr = (wave >> 1) * 64, wc = (wave & 1) * 64;
  const int l15 = lane & 15, l4 = lane >> 4;

  const int cpx = gridDim.x >> 3;
  const int wg = (blockIdx.x & 7) * cpx + (blockIdx.x >> 3);
  const int m0 = (wg / NT) * 128, n0 = (wg % NT) * 128;

  f32x4 acc[4][4];
#pragma unroll
  for (int i = 0; i < 4; ++i)
#pragma unroll
    for (int j = 0; j < 4; ++j) acc[i][j] = (f32x4){0.f, 0.f, 0.f, 0.f};

  const int srow = tid >> 2;          // 0..63
  const int scol = (tid & 3) * 8;     // k-elem offset
  const __bf16* Ag = A + (size_t)(m0 + srow) * K + scol;
  const __bf16* Bg = Bm + (size_t)(n0 + srow) * K + scol;

  for (int k0 = 0; k0 < K; k0 += 32) {
#pragma unroll
    for (int it = 0; it < 2; ++it) {
      GLD16(Ag + (size_t)it * 64 * K + k0, smA + it * 4096 + wave * 1024);
      GLD16(Bg + (size_t)it * 64 * K + k0, smB + it * 4096 + wave * 1024);
    }
    __syncthreads();
    bf16x8 af[4], bfr[4];
#pragma unroll
    for (int mi = 0; mi < 4; ++mi)
      af[mi] = *(const bf16x8*)(smA + (wr + mi * 16 + l15) * 64 + l4 * 16);
#pragma unroll
    for (int ni = 0; ni < 4; ++ni)
      bfr[ni] = *(const bf16x8*)(smB + (wc + ni * 16 + l15) * 64 + l4 * 16);
#pragma unroll
    for (int mi = 0; mi < 4; ++mi)
#pragma unroll
      for (int ni = 0; ni < 4; ++ni)
        acc[mi][ni] = __builtin_amdgcn_mfma_f32_16x16x32_bf16(af[mi], bfr[ni], acc[mi][ni], 0, 0, 0);
    __syncthreads();
  }

#pragma unroll
  for (int ni = 0; ni < 4; ++ni) {
    int n = n0 + wc + ni * 16 + l15;
    float bv = bias[n];
#pragma unroll
    for (int mi = 0; mi < 4; ++mi) {
#pragma unroll
      for (int r = 0; r < 4; ++r) {
        int m = m0 + wr + mi * 16 + l4 * 4 + r;
        float v = acc[mi][ni][r] + bv;
        if (GELU) v = gelu_f(v);
        outB[(size_t)m * N + n] = (__bf16)v;
      }
    }
  }
}

// -------- lm-head GEMM: 256x256 tile, 8 waves, BK=64, double-buffered 128KB LDS,
// phase-split schedule with counted vmcnt (never 0 in steady state), both-sides
// LDS XOR swizzle, fused softmax partials + LDS-restaged aligned stores.
// C[v][pos] = sum_k lmT[v][k] * dbuf[pos][k]; out to outF[1 + b*V*T + v*T + t].
__global__ __launch_bounds__(512) void gemm256lm(
    const __bf16* __restrict__ A, const __bf16* __restrict__ Bm,
    float* __restrict__ outF, float* __restrict__ pm, float* __restrict__ ps) {
  __shared__ __align__(16) char LDS[131072];
  const int tid = threadIdx.x;
  const int lane = tid & 63, wave = tid >> 6;
  const int wm = wave >> 2, wn = wave & 3;   // 2 x 4 wave grid
  const int l15 = lane & 15, l4 = lane >> 4;

  const int cpx = (int)gridDim.x >> 3;
  const int wg = ((int)blockIdx.x & 7) * cpx + ((int)blockIdx.x >> 3);
  const int m0 = (wg >> 3) * 256, n0 = (wg & 7) * 256;

  f32x4 acc[8][4];
#pragma unroll
  for (int i = 0; i < 8; ++i)
#pragma unroll
    for (int j = 0; j < 4; ++j) acc[i][j] = (f32x4){0.f, 0.f, 0.f, 0.f};

  // staging: 8 GLD16 per K-tile (A: 4x64rows, B: 4x64rows), row = 128B of K-elems
  const int srow = tid >> 3;                 // 0..63
  const int scolb = (tid & 7) << 4;          // byte col 0..112
  const int scole = (scolb ^ ((srow & 7) << 4)) >> 1;   // pre-swizzled source elem
  const __bf16* pA[4];
  const __bf16* pB[4];
#pragma unroll
  for (int ld = 0; ld < 4; ++ld) {
    pA[ld] = A + (size_t)(m0 + ld * 64 + srow) * 1024 + scole;
    pB[ld] = Bm + (size_t)(n0 + ld * 64 + srow) * 1024 + scole;
  }
  // prologue: issue K-tile 0 into buf0
#pragma unroll
  for (int ld = 0; ld < 4; ++ld) {
    GLD16(pA[ld], LDS + ld * 8192 + wave * 1024);
    GLD16(pB[ld], LDS + 32768 + ld * 8192 + wave * 1024);
    pA[ld] += 64; pB[ld] += 64;
  }

  const int rsw = (l15 & 7) << 4;            // read-side swizzle XOR
  const int bRow = ((wn & 1) * 64 + l15) * 128;
  const int bHalf = 32768 + (wn >> 1) * 16384;
  const int aBase = wm * 16384 + l15 * 128;

  for (int t = 0; t < 16; ++t) {
    const int cb = (t & 1) << 16;            // current buffer base
    const int nb = cb ^ 65536;               // next buffer
    if (t < 15) {
#pragma unroll
      for (int ld = 0; ld < 4; ++ld) {
        GLD16(pA[ld], LDS + nb + ld * 8192 + wave * 1024);
        GLD16(pB[ld], LDS + nb + 32768 + ld * 8192 + wave * 1024);
        pA[ld] += 64; pB[ld] += 64;
      }
      asm volatile("s_waitcnt vmcnt(8)" ::: "memory");   // tile t landed; t+1 in flight
    } else {
      asm volatile("s_waitcnt vmcnt(0)" ::: "memory");   // last tile: drain
    }
    __builtin_amdgcn_s_barrier();
    asm volatile("" ::: "memory");
    // B fragments for the whole K-tile (held across phases)
    bf16x8 bfr[4][2];
#pragma unroll
    for (int ni = 0; ni < 4; ++ni)
#pragma unroll
      for (int kk = 0; kk < 2; ++kk)
        bfr[ni][kk] = *(const bf16x8*)(LDS + cb + bHalf + bRow + ni * 2048 +
                                       ((kk * 64 + l4 * 16) ^ rsw));
    // 4 phases: m-quadrants
#pragma unroll
    for (int p = 0; p < 4; ++p) {
      bf16x8 af[2][2];
#pragma unroll
      for (int mi2 = 0; mi2 < 2; ++mi2)
#pragma unroll
        for (int kk = 0; kk < 2; ++kk)
          af[mi2][kk] = *(const bf16x8*)(LDS + cb + aBase + (p * 2 + mi2) * 2048 +
                                         ((kk * 64 + l4 * 16) ^ rsw));
      __builtin_amdgcn_s_barrier();
      asm volatile("s_waitcnt lgkmcnt(0)" ::: "memory");
      __builtin_amdgcn_sched_barrier(0);
      __builtin_amdgcn_s_setprio(1);
#pragma unroll
      for (int mi2 = 0; mi2 < 2; ++mi2)
#pragma unroll
        for (int ni = 0; ni < 4; ++ni)
#pragma unroll
          for (int kk = 0; kk < 2; ++kk)
            acc[p * 2 + mi2][ni] = __builtin_amdgcn_mfma_f32_16x16x32_bf16(
                af[mi2][kk], bfr[ni][kk], acc[p * 2 + mi2][ni], 0, 0, 0);
      __builtin_amdgcn_s_setprio(0);
      __builtin_amdgcn_s_barrier();
      asm volatile("" ::: "memory");
    }
  }

  // ---- fused softmax partials: 2 stripes of 64 v per wave
#pragma unroll
  for (int st = 0; st < 2; ++st) {
    const int ch = (m0 >> 6) + wm * 2 + st;
#pragma unroll
    for (int ni = 0; ni < 4; ++ni) {
      const int pos = n0 + wn * 64 + ni * 16 + l15;
      float mloc = -1e30f, sloc = 0.f;
#pragma unroll
      for (int ms = 0; ms < 4; ++ms) {
        const int vb = m0 + wm * 128 + (st * 4 + ms) * 16 + l4 * 4;
#pragma unroll
        for (int r = 0; r < 4; ++r)
          if (vb + r < VSZ) mloc = fmaxf(mloc, acc[st * 4 + ms][ni][r]);
      }
#pragma unroll
      for (int ms = 0; ms < 4; ++ms) {
        const int vb = m0 + wm * 128 + (st * 4 + ms) * 16 + l4 * 4;
#pragma unroll
        for (int r = 0; r < 4; ++r)
          if (vb + r < VSZ) sloc += __expf(acc[st * 4 + ms][ni][r] - mloc);
      }
#pragma unroll
      for (int off = 16; off <= 32; off <<= 1) {
        float mo = __shfl_xor(mloc, off, 64);
        float so = __shfl_xor(sloc, off, 64);
        float nm = fmaxf(mloc, mo);
        sloc = sloc * __expf(mloc - nm) + so * __expf(mo - nm);
        mloc = nm;
      }
      if (l4 == 0) {
        pm[(size_t)ch * NPOS + pos] = mloc;
        ps[(size_t)ch * NPOS + pos] = sloc;
      }
    }
  }

  // ---- LDS-restaged aligned stores: 8 chunks of 32 v-rows x 256 t
  float* eps = (float*)LDS;                  // [32][268] f32 = 34.3 KB
  const int bb = n0 >> 9, t0g = n0 & 511;
  float* outG = outF + 1 + (size_t)bb * VSZ * TSZ + t0g;
  const int r32 = tid >> 4, j16 = tid & 15;
#pragma unroll
  for (int q = 0; q < 8; ++q) {
    __builtin_amdgcn_s_barrier();
    asm volatile("" ::: "memory");
    if (wm == (q >> 2)) {
      const int mib = (q & 3) * 2;
#pragma unroll
      for (int mi2 = 0; mi2 < 2; ++mi2)
#pragma unroll
        for (int ni = 0; ni < 4; ++ni)
#pragma unroll
          for (int r = 0; r < 4; ++r)
            eps[(mi2 * 16 + l4 * 4 + r) * 268 + wn * 64 + ni * 16 + l15] =
                acc[mib + mi2][ni][r];
    }
    __builtin_amdgcn_s_barrier();
    asm volatile("" ::: "memory");
    const int v = m0 + q * 32 + r32;
    if (v < VSZ) {
      float* gp = outG + (size_t)v * TSZ;
#pragma unroll
      for (int c = 0; c < 4; ++c) {
        const float* lp = &eps[r32 * 268 + c * 64 + j16 * 4];
        float* g = gp + c * 64 + j16 * 4;
        g[0] = lp[0]; g[1] = lp[1]; g[2] = lp[2]; g[3] = lp[3];
      }
    }
  }
}

// -------- merge softmax partials per position (4 independent chains; 788 = 4*197)
__global__ __launch_bounds__(256) void lsemerge_kernel(const float* __restrict__ pm,
                                                       const float* __restrict__ ps,
                                                       const float* __restrict__ outF,
                                                       const int* __restrict__ labels,
                                                       float* __restrict__ contrib) {
  int pos = blockIdx.x * 256 + threadIdx.x;   // 0..2047
  float m[4] = {-1e30f, -1e30f, -1e30f, -1e30f};
  float s[4] = {0.f, 0.f, 0.f, 0.f};
  for (int c = 0; c < NCH; c += 4) {
#pragma unroll
    for (int j = 0; j < 4; ++j) {
      float cm = pm[(size_t)(c + j) * NPOS + pos];
      float cs = ps[(size_t)(c + j) * NPOS + pos];
      float nm = fmaxf(m[j], cm);
      s[j] = s[j] * __expf(m[j] - nm) + cs * __expf(cm - nm);
      m[j] = nm;
    }
  }
#pragma unroll
  for (int j = 1; j < 4; ++j) {
    float nm = fmaxf(m[0], m[j]);
    s[0] = s[0] * __expf(m[0] - nm) + s[j] * __expf(m[j] - nm);
    m[0] = nm;
  }
  float lse = m[0] + logf(s[0]);
  int b = pos >> 9, t = pos & 511;
  int lab = labels[pos];
  float x = outF[1 + (size_t)b * VSZ * TSZ + (size_t)lab * TSZ + t];
  contrib[pos] = lse - x;
}

__global__ __launch_bounds__(256) void lossfinal_kernel(const float* __restrict__ contrib,
                                                        float* __restrict__ dout) {
  __shared__ float red[256];
  int tid = threadIdx.x;
  float a = 0.f;
  for (int i = tid; i < NPOS; i += 256) a += contrib[i];
  red[tid] = a;
  __syncthreads();
  for (int off = 128; off; off >>= 1) {
    if (tid < off) red[tid] += red[tid + off];
    __syncthreads();
  }
  if (tid == 0) dout[0] = red[0] / (float)NPOS;
}

extern "C" void kernel_launch(void* const* d_in, const int* in_sizes, int n_in,
                              void* d_out, int out_size, void* d_ws, size_t ws_size,
                              hipStream_t stream) {
  const int* input_ids = (const int*)d_in[0];
  const int* labels    = (const int*)d_in[1];
  const float* wte     = (const float*)d_in[2];
  const float* enc_w1  = (const float*)d_in[3];
  const float* enc_b1  = (const float*)d_in[4];
  const float* enc_w2  = (const float*)d_in[5];
  const float* enc_b2  = (const float*)d_in[6];
  const float* proj_w  = (const float*)d_in[7];
  const float* proj_b  = (const float*)d_in[8];
  const float* dec_w1  = (const float*)d_in[9];
  const float* dec_b1  = (const float*)d_in[10];
  const float* dec_w2  = (const float*)d_in[11];
  const float* dec_b2  = (const float*)d_in[12];
  const float* lm_w    = (const float*)d_in[13];
  float* outF = (float*)d_out;

  char* w = (char*)d_ws;
  size_t off = 0;
  __bf16* lmT   = (__bf16*)(w + off); off += (size_t)VPAD * DSZ * 2;      // 103.3 MB
  __bf16* w1T   = (__bf16*)(w + off); off += (size_t)HSZ * DSZ * 2;       // 8 MB
  __bf16* w2T   = (__bf16*)(w + off); off += (size_t)DSZ * HSZ * 2;       // 8 MB
  __bf16* projT = (__bf16*)(w + off); off += (size_t)DSZ * 512 * 2;       // 1 MB
  __bf16* win   = (__bf16*)(w + off); off += (size_t)2048 * 512 * 2;      // 2 MB
  __bf16* pbuf  = (__bf16*)(w + off); off += (size_t)2048 * DSZ * 2;      // 4 MB
  __bf16* abuf  = (__bf16*)(w + off); off += (size_t)2048 * HSZ * 2;      // 16 MB
  __bf16* dbuf  = (__bf16*)(w + off); off += (size_t)2048 * DSZ * 2;      // 4 MB
  float* e      = (float*)(w + off);  off += (size_t)BSZ * DSZ * 4;
  float* t1p    = (float*)(w + off);  off += (size_t)BSZ * KS1 * HSZ * 4;   // 512 KB
  float* ep     = (float*)(w + off);  off += (size_t)BSZ * KS2 * DSZ * 4;   // 256 KB
  float* contrib= (float*)(w + off);  off += (size_t)NPOS * 4;
  // softmax partials alias abuf (free after gemm3): 788*2048*4*2 = 12.9 MB <= 16 MB
  float* pm = (float*)abuf;
  float* ps = pm + (size_t)NCH * NPOS;
  (void)ws_size; (void)in_sizes; (void)n_in; (void)out_size;

  // weight transposes (f32 -> bf16, K-contiguous)
  transpose_conv64<<<dim3(VPAD / 64, DSZ / 64), 256, 0, stream>>>(lm_w, lmT, DSZ, VSZ, VPAD);
  transpose_conv64<<<dim3(HSZ / 64, DSZ / 64), 256, 0, stream>>>(dec_w1, w1T, DSZ, HSZ, HSZ);
  transpose_conv64<<<dim3(DSZ / 64, HSZ / 64), 256, 0, stream>>>(dec_w2, w2T, HSZ, DSZ, DSZ);
  transpose_conv64<<<dim3(DSZ / 64, 512 / 64), 256, 0, stream>>>(proj_w, projT, 512, DSZ, DSZ);

  // encoder on last token only (K-split for parallelism)
  enc1p_kernel<<<dim3(BSZ, HSZ / 256, KS1), 256, 0, stream>>>(input_ids, wte, enc_w1, t1p);
  enc2p_kernel<<<dim3(BSZ, DSZ / 256, KS2), 256, 0, stream>>>(t1p, enc_b1, enc_w2, ep);
  enc2c_kernel<<<dim3(BSZ * DSZ / 256), 256, 0, stream>>>(ep, enc_b2, e);
  win_kernel<<<2048, 256, 0, stream>>>(e, win);

  // GEMM chain (1D grids, all divisible by 8 for the XCD swizzle)
  gemm128<0><<<128, 256, 0, stream>>>(win, projT, proj_b, pbuf, 8, 2048, DSZ, 512);
  gemm128<1><<<512, 256, 0, stream>>>(pbuf, w1T, dec_b1, abuf, 32, 2048, HSZ, DSZ);
  gemm128<0><<<128, 256, 0, stream>>>(abuf, w2T, dec_b2, dbuf, 8, 2048, DSZ, HSZ);
  // lm head: 197 m-tiles x 8 n-tiles = 1576 blocks
  gemm256lm<<<1576, 512, 0, stream>>>(lmT, dbuf, outF, pm, ps);

  // loss: merge partials + mean
  lsemerge_kernel<<<dim3(NPOS / 256), 256, 0, stream>>>(pm, ps, outF, labels, contrib);
  lossfinal_kernel<<<1, 256, 0, stream>>>(contrib, outF);
}

// Round 6
// 651.935 us; speedup vs baseline: 1.1702x; 1.1702x over previous
//
#include <hip/hip_runtime.h>

#define VSZ 50257
#define DSZ 1024
#define TSZ 512
#define BSZ 4
#define HSZ 4096
#define VPAD 50432   // 394*128
#define NCH (VPAD / 64)   // 788 v-stripes of 64
#define NPOS 2048

typedef __attribute__((ext_vector_type(8))) __bf16 bf16x8;
typedef __attribute__((ext_vector_type(4))) float f32x4;

#define GLD16(gp, lp) __builtin_amdgcn_global_load_lds( \
  (const __attribute__((address_space(1))) unsigned int*)(gp), \
  (__attribute__((address_space(3))) unsigned int*)(lp), 16, 0, 0)

__device__ __forceinline__ float gelu_f(float x) {
  float x3 = x * x * x;
  float u = 0.7978845608028654f * (x + 0.044715f * x3);
  return 0.5f * x * (1.f + tanhf(u));
}

// -------- all weight transposes fused: f32 (R x C) -> bf16 (Cpad x R), 64x64 tiles
__global__ __launch_bounds__(256) void transpose_all(
    const float* __restrict__ lm_w, const float* __restrict__ dw1,
    const float* __restrict__ dw2, const float* __restrict__ pw,
    __bf16* __restrict__ lmT, __bf16* __restrict__ w1T,
    __bf16* __restrict__ w2T, __bf16* __restrict__ projT) {
  __shared__ float tile[64][65];
  int bid = blockIdx.x;
  const float* src; __bf16* dst; int R, C, Cpad, bx, by;
  if (bid < 12608)      { src = lm_w; dst = lmT;  R = DSZ; C = VSZ; Cpad = VPAD; bx = bid % 788; by = bid / 788; }
  else if (bid < 13632) { int b = bid - 12608; src = dw1; dst = w1T; R = DSZ; C = HSZ; Cpad = HSZ; bx = b % 64; by = b / 64; }
  else if (bid < 14656) { int b = bid - 13632; src = dw2; dst = w2T; R = HSZ; C = DSZ; Cpad = DSZ; bx = b % 16; by = b / 16; }
  else                  { int b = bid - 14656; src = pw;  dst = projT; R = 512; C = DSZ; Cpad = DSZ; bx = b % 16; by = b / 16; }
  int c0 = bx * 64, r0 = by * 64;
  int tid = threadIdx.x;
  int wv = tid >> 6, ln = tid & 63;
  int c = c0 + ln;
#pragma unroll 4
  for (int i = 0; i < 16; ++i) {
    int r = i * 4 + wv;
    tile[r][ln] = (c < C) ? src[(size_t)(r0 + r) * C + c] : 0.f;
  }
  __syncthreads();
  int ccb = tid >> 4;
  int r4 = (tid & 15) * 4;
#pragma unroll
  for (int j = 0; j < 4; ++j) {
    int cc = ccb + j * 16;
    union { ushort4 u4; ushort s[4]; } pk;
#pragma unroll
    for (int q = 0; q < 4; ++q) {
      union { __bf16 b; ushort s; } cv;
      cv.b = (__bf16)tile[r4 + q][cc];
      pk.s[q] = cv.s;
    }
    if (c0 + cc < Cpad)
      *(ushort4*)(dst + (size_t)(c0 + cc) * R + r0 + r4) = pk.u4;
  }
}

// -------- encoder layer 1 partials: K-split dot over d-chunk of 128
#define KS1 8
__global__ __launch_bounds__(256) void enc1p_kernel(const int* __restrict__ ids,
                                                    const float* __restrict__ wte,
                                                    const float* __restrict__ w1,
                                                    float* __restrict__ t1p) {
  int b = blockIdx.x;
  int h = blockIdx.y * 256 + threadIdx.x;
  int kc = blockIdx.z;
  int tok = ids[b * TSZ + (TSZ - 1)];
  const float* ev = wte + (size_t)tok * DSZ + kc * (DSZ / KS1);
  const float* w = w1 + (size_t)kc * (DSZ / KS1) * HSZ + h;
  float s = 0.f;
#pragma unroll 4
  for (int d = 0; d < DSZ / KS1; ++d) s += ev[d] * w[(size_t)d * HSZ];
  t1p[((size_t)(b * KS1 + kc)) * HSZ + h] = s;
}

// -------- encoder layer 2 partials (enc1 combine + gelu fused in):
#define KS2 16
__global__ __launch_bounds__(256) void enc2p_kernel(const float* __restrict__ t1p,
                                                    const float* __restrict__ b1,
                                                    const float* __restrict__ w2,
                                                    float* __restrict__ ep) {
  __shared__ float ts[256];
  int b = blockIdx.x;
  int i = blockIdx.y * 256 + threadIdx.x;
  int kc = blockIdx.z;
  int h = kc * 256 + threadIdx.x;
  float s0 = b1[h];
#pragma unroll
  for (int cc = 0; cc < KS1; ++cc) s0 += t1p[((size_t)(b * KS1 + cc)) * HSZ + h];
  ts[threadIdx.x] = gelu_f(s0);
  __syncthreads();
  const float* w = w2 + (size_t)kc * 256 * DSZ + i;
  float s = 0.f;
#pragma unroll 4
  for (int j = 0; j < 256; ++j) s += ts[j] * w[(size_t)j * DSZ];
  ep[((size_t)(b * KS2 + kc)) * DSZ + i] = s;
}

__global__ __launch_bounds__(256) void enc2c_kernel(const float* __restrict__ ep,
                                                    const float* __restrict__ b2,
                                                    float* __restrict__ e) {
  int idx = blockIdx.x * 256 + threadIdx.x;
  int b = idx >> 10, i = idx & (DSZ - 1);
  float s = b2[i];
#pragma unroll
  for (int kc = 0; kc < KS2; ++kc) s += ep[((size_t)(b * KS2 + kc)) * DSZ + i];
  e[idx] = s;
}

// -------- windows: win[b*T+t][j] = bf16(e[b][t+j])
__global__ void win_kernel(const float* __restrict__ e, __bf16* __restrict__ win) {
  int blk = blockIdx.x;
  int b = blk >> 9, t = blk & 511;
  const float* eb = e + b * DSZ;
  for (int j = threadIdx.x; j < 512; j += 256)
    win[(size_t)blk * 512 + j] = (__bf16)eb[t + j];
}

// -------- pipelined GEMM: C[m][n] = sum_k A[m][k]*B[n][k], 128x128 tile, 4 waves,
// BK=32 double-buffered (32 KiB LDS -> 4 blocks/CU), counted vmcnt(4),
// rotation LDS layout: k-slot phys = (logical + (row>>1)) & 3 -> 2-way banks (free).
// MODE 0: bf16 out row-major [M][N] + bias, opt gelu.
// MODE 1: lm head: fused softmax partials + LDS-restaged f32 stores.
template<int GELU, int MODE>
__global__ __launch_bounds__(256, 4) void gemmP(
    const __bf16* __restrict__ A, const __bf16* __restrict__ Bm,
    const float* __restrict__ bias, __bf16* __restrict__ outB,
    float* __restrict__ outF, float* __restrict__ pm, float* __restrict__ ps,
    int NT, int N, int K) {
  __shared__ __align__(16) char SM[32768];   // 2 bufs x (A 8K + B 8K); MODE1 epi reuse
  const int tid = threadIdx.x;
  const int lane = tid & 63;
  const int wave = tid >> 6;
  const int wr = (wave >> 1) * 64, wc = (wave & 1) * 64;
  const int l15 = lane & 15, l4 = lane >> 4;

  const int cpx = (int)gridDim.x >> 3;
  const int wg = ((int)blockIdx.x & 7) * cpx + ((int)blockIdx.x >> 3);
  const int m0 = (wg / NT) * 128, n0 = (wg % NT) * 128;

  f32x4 acc[4][4];
#pragma unroll
  for (int i = 0; i < 4; ++i)
#pragma unroll
    for (int j = 0; j < 4; ++j) acc[i][j] = (f32x4){0.f, 0.f, 0.f, 0.f};

  // staging geometry (4 GLD16/thread/tile): sweep s covers rows s*64..s*64+63
  const int phys = lane & 3;
  const int row0 = wave * 16 + (lane >> 2);
  const int row1 = row0 + 64;
  const int orig0 = (phys - (row0 >> 1)) & 3;
  const int orig1 = (phys - (row1 >> 1)) & 3;
  const size_t rs = (size_t)K * 2;           // row stride bytes
  const char* a0 = (const char*)A + (size_t)(m0 + row0) * rs + orig0 * 16;
  const char* a1 = (const char*)A + (size_t)(m0 + row1) * rs + orig1 * 16;
  const char* b0 = (const char*)Bm + (size_t)(n0 + row0) * rs + orig0 * 16;
  const char* b1 = (const char*)Bm + (size_t)(n0 + row1) * rs + orig1 * 16;

#define STAGEP(tt, bufb) do { \
    GLD16(a0 + (size_t)(tt) * 64, SM + (bufb) + wave * 1024); \
    GLD16(a1 + (size_t)(tt) * 64, SM + (bufb) + 4096 + wave * 1024); \
    GLD16(b0 + (size_t)(tt) * 64, SM + (bufb) + 8192 + wave * 1024); \
    GLD16(b1 + (size_t)(tt) * 64, SM + (bufb) + 12288 + wave * 1024); \
  } while (0)

  const int KT = K >> 5;
  STAGEP(0, 0);
  for (int t = 0; t < KT; ++t) {
    const int cb = (t & 1) << 14;
    if (t + 1 < KT) {
      STAGEP(t + 1, cb ^ 16384);
      asm volatile("s_waitcnt vmcnt(4)" ::: "memory");   // tile t landed, t+1 in flight
    } else {
      asm volatile("s_waitcnt vmcnt(0)" ::: "memory");
    }
    __builtin_amdgcn_s_barrier();
    asm volatile("" ::: "memory");
    bf16x8 af[4], bfr[4];
#pragma unroll
    for (int mi = 0; mi < 4; ++mi) {
      const int arow = wr + mi * 16 + l15;
      af[mi] = *(const bf16x8*)(SM + cb + arow * 64 + (((l4 + (arow >> 1)) & 3) << 4));
    }
#pragma unroll
    for (int ni = 0; ni < 4; ++ni) {
      const int brow = wc + ni * 16 + l15;
      bfr[ni] = *(const bf16x8*)(SM + cb + 8192 + brow * 64 + (((l4 + (brow >> 1)) & 3) << 4));
    }
    asm volatile("s_waitcnt lgkmcnt(0)" ::: "memory");
    __builtin_amdgcn_sched_barrier(0);
    __builtin_amdgcn_s_setprio(1);
#pragma unroll
    for (int mi = 0; mi < 4; ++mi)
#pragma unroll
      for (int ni = 0; ni < 4; ++ni)
        acc[mi][ni] = __builtin_amdgcn_mfma_f32_16x16x32_bf16(af[mi], bfr[ni], acc[mi][ni], 0, 0, 0);
    __builtin_amdgcn_s_setprio(0);
    __builtin_amdgcn_s_barrier();
    asm volatile("" ::: "memory");
  }
#undef STAGEP

  if (MODE == 0) {
#pragma unroll
    for (int ni = 0; ni < 4; ++ni) {
      int n = n0 + wc + ni * 16 + l15;
      float bv = bias[n];
#pragma unroll
      for (int mi = 0; mi < 4; ++mi) {
#pragma unroll
        for (int r = 0; r < 4; ++r) {
          int m = m0 + wr + mi * 16 + l4 * 4 + r;
          float v = acc[mi][ni][r] + bv;
          if (GELU) v = gelu_f(v);
          outB[(size_t)m * N + n] = (__bf16)v;
        }
      }
    }
  } else {
    // ---- fused softmax partials per 64-v stripe
    const int ch = (m0 + wr) >> 6;
#pragma unroll
    for (int ni = 0; ni < 4; ++ni) {
      int n = n0 + wc + ni * 16 + l15;   // pos = b*T + t
      float mloc = -1e30f, sloc = 0.f;
#pragma unroll
      for (int mi = 0; mi < 4; ++mi) {
        int vbase = m0 + wr + mi * 16 + l4 * 4;
#pragma unroll
        for (int r = 0; r < 4; ++r)
          if (vbase + r < VSZ) mloc = fmaxf(mloc, acc[mi][ni][r]);
      }
#pragma unroll
      for (int mi = 0; mi < 4; ++mi) {
        int vbase = m0 + wr + mi * 16 + l4 * 4;
#pragma unroll
        for (int r = 0; r < 4; ++r)
          if (vbase + r < VSZ) sloc += __expf(acc[mi][ni][r] - mloc);
      }
#pragma unroll
      for (int off = 16; off <= 32; off <<= 1) {
        float mo = __shfl_xor(mloc, off, 64);
        float so = __shfl_xor(sloc, off, 64);
        float nm = fmaxf(mloc, mo);
        sloc = sloc * __expf(mloc - nm) + so * __expf(mo - nm);
        mloc = nm;
      }
      if (l4 == 0) {
        pm[(size_t)ch * NPOS + n] = mloc;
        ps[(size_t)ch * NPOS + n] = sloc;
      }
    }

    // ---- LDS-restaged aligned f32 stores: 4 quarters of 32 v-rows x 128 t
    float* epi = (float*)SM;                 // [32][132] = 16.9 KB
    const int bb = n0 >> 9, t0 = n0 & 511;
    float* outG = outF + 1 + (size_t)bb * VSZ * TSZ + t0;
    const int trow = tid >> 5;
    const int lofs = (tid & 31) * 4;
#pragma unroll
    for (int q = 0; q < 4; ++q) {
      __builtin_amdgcn_s_barrier();
      asm volatile("" ::: "memory");
      if ((wave >> 1) == (q >> 1)) {
        const int miBase = (q & 1) * 2;
#pragma unroll
        for (int mi2 = 0; mi2 < 2; ++mi2)
#pragma unroll
          for (int ni = 0; ni < 4; ++ni)
#pragma unroll
            for (int r = 0; r < 4; ++r)
              epi[(mi2 * 16 + l4 * 4 + r) * 132 + wc + ni * 16 + l15] =
                  acc[miBase + mi2][ni][r];
      }
      __builtin_amdgcn_s_barrier();
      asm volatile("" ::: "memory");
#pragma unroll
      for (int p = 0; p < 4; ++p) {
        int row = p * 8 + trow;
        int v = m0 + q * 32 + row;
        if (v < VSZ) {
          f32x4 val = *(const f32x4*)&epi[row * 132 + lofs];
          float* gp = outG + (size_t)v * TSZ + lofs;
          gp[0] = val[0]; gp[1] = val[1]; gp[2] = val[2]; gp[3] = val[3];
        }
      }
    }
  }
}

// -------- merge softmax partials per position (4 independent chains; 788 = 4*197)
__global__ __launch_bounds__(256) void lsemerge_kernel(const float* __restrict__ pm,
                                                       const float* __restrict__ ps,
                                                       const float* __restrict__ outF,
                                                       const int* __restrict__ labels,
                                                       float* __restrict__ contrib) {
  int pos = blockIdx.x * 256 + threadIdx.x;
  float m[4] = {-1e30f, -1e30f, -1e30f, -1e30f};
  float s[4] = {0.f, 0.f, 0.f, 0.f};
  for (int c = 0; c < NCH; c += 4) {
#pragma unroll
    for (int j = 0; j < 4; ++j) {
      float cm = pm[(size_t)(c + j) * NPOS + pos];
      float cs = ps[(size_t)(c + j) * NPOS + pos];
      float nm = fmaxf(m[j], cm);
      s[j] = s[j] * __expf(m[j] - nm) + cs * __expf(cm - nm);
      m[j] = nm;
    }
  }
#pragma unroll
  for (int j = 1; j < 4; ++j) {
    float nm = fmaxf(m[0], m[j]);
    s[0] = s[0] * __expf(m[0] - nm) + s[j] * __expf(m[j] - nm);
    m[0] = nm;
  }
  float lse = m[0] + logf(s[0]);
  int b = pos >> 9, t = pos & 511;
  int lab = labels[pos];
  float x = outF[1 + (size_t)b * VSZ * TSZ + (size_t)lab * TSZ + t];
  contrib[pos] = lse - x;
}

__global__ __launch_bounds__(256) void lossfinal_kernel(const float* __restrict__ contrib,
                                                        float* __restrict__ dout) {
  __shared__ float red[256];
  int tid = threadIdx.x;
  float a = 0.f;
  for (int i = tid; i < NPOS; i += 256) a += contrib[i];
  red[tid] = a;
  __syncthreads();
  for (int off = 128; off; off >>= 1) {
    if (tid < off) red[tid] += red[tid + off];
    __syncthreads();
  }
  if (tid == 0) dout[0] = red[0] / (float)NPOS;
}

extern "C" void kernel_launch(void* const* d_in, const int* in_sizes, int n_in,
                              void* d_out, int out_size, void* d_ws, size_t ws_size,
                              hipStream_t stream) {
  const int* input_ids = (const int*)d_in[0];
  const int* labels    = (const int*)d_in[1];
  const float* wte     = (const float*)d_in[2];
  const float* enc_w1  = (const float*)d_in[3];
  const float* enc_b1  = (const float*)d_in[4];
  const float* enc_w2  = (const float*)d_in[5];
  const float* enc_b2  = (const float*)d_in[6];
  const float* proj_w  = (const float*)d_in[7];
  const float* proj_b  = (const float*)d_in[8];
  const float* dec_w1  = (const float*)d_in[9];
  const float* dec_b1  = (const float*)d_in[10];
  const float* dec_w2  = (const float*)d_in[11];
  const float* dec_b2  = (const float*)d_in[12];
  const float* lm_w    = (const float*)d_in[13];
  float* outF = (float*)d_out;

  char* w = (char*)d_ws;
  size_t off = 0;
  __bf16* lmT   = (__bf16*)(w + off); off += (size_t)VPAD * DSZ * 2;      // 103.3 MB
  __bf16* w1T   = (__bf16*)(w + off); off += (size_t)HSZ * DSZ * 2;       // 8 MB
  __bf16* w2T   = (__bf16*)(w + off); off += (size_t)DSZ * HSZ * 2;       // 8 MB
  __bf16* projT = (__bf16*)(w + off); off += (size_t)DSZ * 512 * 2;       // 1 MB
  __bf16* win   = (__bf16*)(w + off); off += (size_t)2048 * 512 * 2;      // 2 MB
  __bf16* pbuf  = (__bf16*)(w + off); off += (size_t)2048 * DSZ * 2;      // 4 MB
  __bf16* abuf  = (__bf16*)(w + off); off += (size_t)2048 * HSZ * 2;      // 16 MB
  __bf16* dbuf  = (__bf16*)(w + off); off += (size_t)2048 * DSZ * 2;      // 4 MB
  float* e      = (float*)(w + off);  off += (size_t)BSZ * DSZ * 4;
  float* t1p    = (float*)(w + off);  off += (size_t)BSZ * KS1 * HSZ * 4;
  float* ep     = (float*)(w + off);  off += (size_t)BSZ * KS2 * DSZ * 4;
  float* contrib= (float*)(w + off);  off += (size_t)NPOS * 4;
  // softmax partials alias abuf (free after dec2): 788*2048*4*2 = 12.9 MB <= 16 MB
  float* pm = (float*)abuf;
  float* ps = pm + (size_t)NCH * NPOS;
  (void)ws_size; (void)in_sizes; (void)n_in; (void)out_size;

  // all weight transposes in one dispatch
  transpose_all<<<14784, 256, 0, stream>>>(lm_w, dec_w1, dec_w2, proj_w, lmT, w1T, w2T, projT);

  // encoder on last token only (K-split for parallelism)
  enc1p_kernel<<<dim3(BSZ, HSZ / 256, KS1), 256, 0, stream>>>(input_ids, wte, enc_w1, t1p);
  enc2p_kernel<<<dim3(BSZ, DSZ / 256, KS2), 256, 0, stream>>>(t1p, enc_b1, enc_w2, ep);
  enc2c_kernel<<<dim3(BSZ * DSZ / 256), 256, 0, stream>>>(ep, enc_b2, e);
  win_kernel<<<2048, 256, 0, stream>>>(e, win);

  // GEMM chain (1D grids, all divisible by 8 for the XCD swizzle)
  gemmP<0, 0><<<128, 256, 0, stream>>>(win, projT, proj_b, pbuf, nullptr, nullptr, nullptr, 8, DSZ, 512);
  gemmP<1, 0><<<512, 256, 0, stream>>>(pbuf, w1T, dec_b1, abuf, nullptr, nullptr, nullptr, 32, HSZ, DSZ);
  gemmP<0, 0><<<128, 256, 0, stream>>>(abuf, w2T, dec_b2, dbuf, nullptr, nullptr, nullptr, 8, DSZ, HSZ);
  // lm head: 394 m-tiles x 16 n-tiles = 6304 blocks
  gemmP<0, 1><<<6304, 256, 0, stream>>>(lmT, dbuf, nullptr, nullptr, outF, pm, ps, 16, NPOS, DSZ);

  // loss: merge partials + mean
  lsemerge_kernel<<<dim3(NPOS / 256), 256, 0, stream>>>(pm, ps, outF, labels, contrib);
  lossfinal_kernel<<<1, 256, 0, stream>>>(contrib, outF);
}

// Round 7
// 548.514 us; speedup vs baseline: 1.3908x; 1.1885x over previous
//
#include <hip/hip_runtime.h>

#define VSZ 50257
#define DSZ 1024
#define TSZ 512
#define BSZ 4
#define HSZ 4096
#define VPAD 50432   // 394*128
#define NCH (VPAD / 64)   // 788 v-stripes of 64
#define NPOS 2048

typedef __attribute__((ext_vector_type(8))) __bf16 bf16x8;
typedef __attribute__((ext_vector_type(4))) float f32x4;

#define GLD16(gp, lp) __builtin_amdgcn_global_load_lds( \
  (const __attribute__((address_space(1))) unsigned int*)(gp), \
  (__attribute__((address_space(3))) unsigned int*)(lp), 16, 0, 0)

__device__ __forceinline__ float gelu_f(float x) {
  float x3 = x * x * x;
  float u = 0.7978845608028654f * (x + 0.044715f * x3);
  return 0.5f * x * (1.f + tanhf(u));
}

// -------- all weight transposes fused: f32 (R x C) -> bf16/fp8 (Cpad x R), 64x64 tiles
__global__ __launch_bounds__(256) void transpose_all(
    const float* __restrict__ lm_w, const float* __restrict__ dw1,
    const float* __restrict__ dw2, const float* __restrict__ pw,
    unsigned char* __restrict__ lm8, __bf16* __restrict__ w1T,
    __bf16* __restrict__ w2T, __bf16* __restrict__ projT) {
  __shared__ float tile[64][65];
  int bid = blockIdx.x;
  const float* src; __bf16* dst; int R, C, Cpad, bx, by, m8 = 0;
  if (bid < 12608)      { src = lm_w; dst = nullptr; m8 = 1; R = DSZ; C = VSZ; Cpad = VPAD; bx = bid % 788; by = bid / 788; }
  else if (bid < 13632) { int b = bid - 12608; src = dw1; dst = w1T; R = DSZ; C = HSZ; Cpad = HSZ; bx = b % 64; by = b / 64; }
  else if (bid < 14656) { int b = bid - 13632; src = dw2; dst = w2T; R = HSZ; C = DSZ; Cpad = DSZ; bx = b % 16; by = b / 16; }
  else                  { int b = bid - 14656; src = pw;  dst = projT; R = 512; C = DSZ; Cpad = DSZ; bx = b % 16; by = b / 16; }
  int c0 = bx * 64, r0 = by * 64;
  int tid = threadIdx.x;
  int wv = tid >> 6, ln = tid & 63;
  int c = c0 + ln;
#pragma unroll 4
  for (int i = 0; i < 16; ++i) {
    int r = i * 4 + wv;
    tile[r][ln] = (c < C) ? src[(size_t)(r0 + r) * C + c] : 0.f;
  }
  __syncthreads();
  int ccb = tid >> 4;
  int r4 = (tid & 15) * 4;
#pragma unroll
  for (int j = 0; j < 4; ++j) {
    int cc = ccb + j * 16;
    if (c0 + cc >= Cpad) continue;
    if (m8) {
      unsigned int u = __builtin_amdgcn_cvt_pk_fp8_f32(tile[r4 + 0][cc], tile[r4 + 1][cc], 0, 0);
      u = __builtin_amdgcn_cvt_pk_fp8_f32(tile[r4 + 2][cc], tile[r4 + 3][cc], u, 1);
      *(unsigned int*)(lm8 + (size_t)(c0 + cc) * DSZ + r0 + r4) = u;
    } else {
      union { ushort4 u4; ushort s[4]; } pk;
#pragma unroll
      for (int q = 0; q < 4; ++q) {
        union { __bf16 b; ushort s; } cv;
        cv.b = (__bf16)tile[r4 + q][cc];
        pk.s[q] = cv.s;
      }
      *(ushort4*)(dst + (size_t)(c0 + cc) * R + r0 + r4) = pk.u4;
    }
  }
}

// -------- encoder layer 1 partials: K-split dot over d-chunk of 128
#define KS1 8
__global__ __launch_bounds__(256) void enc1p_kernel(const int* __restrict__ ids,
                                                    const float* __restrict__ wte,
                                                    const float* __restrict__ w1,
                                                    float* __restrict__ t1p) {
  int b = blockIdx.x;
  int h = blockIdx.y * 256 + threadIdx.x;
  int kc = blockIdx.z;
  int tok = ids[b * TSZ + (TSZ - 1)];
  const float* ev = wte + (size_t)tok * DSZ + kc * (DSZ / KS1);
  const float* w = w1 + (size_t)kc * (DSZ / KS1) * HSZ + h;
  float s = 0.f;
#pragma unroll 4
  for (int d = 0; d < DSZ / KS1; ++d) s += ev[d] * w[(size_t)d * HSZ];
  t1p[((size_t)(b * KS1 + kc)) * HSZ + h] = s;
}

// -------- encoder layer 2 partials (enc1 combine + gelu fused in):
#define KS2 16
__global__ __launch_bounds__(256) void enc2p_kernel(const float* __restrict__ t1p,
                                                    const float* __restrict__ b1,
                                                    const float* __restrict__ w2,
                                                    float* __restrict__ ep) {
  __shared__ float ts[256];
  int b = blockIdx.x;
  int i = blockIdx.y * 256 + threadIdx.x;
  int kc = blockIdx.z;
  int h = kc * 256 + threadIdx.x;
  float s0 = b1[h];
#pragma unroll
  for (int cc = 0; cc < KS1; ++cc) s0 += t1p[((size_t)(b * KS1 + cc)) * HSZ + h];
  ts[threadIdx.x] = gelu_f(s0);
  __syncthreads();
  const float* w = w2 + (size_t)kc * 256 * DSZ + i;
  float s = 0.f;
#pragma unroll 4
  for (int j = 0; j < 256; ++j) s += ts[j] * w[(size_t)j * DSZ];
  ep[((size_t)(b * KS2 + kc)) * DSZ + i] = s;
}

__global__ __launch_bounds__(256) void enc2c_kernel(const float* __restrict__ ep,
                                                    const float* __restrict__ b2,
                                                    float* __restrict__ e) {
  int idx = blockIdx.x * 256 + threadIdx.x;
  int b = idx >> 10, i = idx & (DSZ - 1);
  float s = b2[i];
#pragma unroll
  for (int kc = 0; kc < KS2; ++kc) s += ep[((size_t)(b * KS2 + kc)) * DSZ + i];
  e[idx] = s;
}

// -------- windows: win[b*T+t][j] = bf16(e[b][t+j])
__global__ void win_kernel(const float* __restrict__ e, __bf16* __restrict__ win) {
  int blk = blockIdx.x;
  int b = blk >> 9, t = blk & 511;
  const float* eb = e + b * DSZ;
  for (int j = threadIdx.x; j < 512; j += 256)
    win[(size_t)blk * 512 + j] = (__bf16)eb[t + j];
}

// -------- pipelined bf16 GEMM (proj/dec1/dec2): 128x128, BK=32 dbuf, vmcnt(4),
// rotation LDS layout. OUT8: write fp8 bytes (for dbuf8) instead of bf16.
template<int GELU, int OUT8>
__global__ __launch_bounds__(256, 4) void gemmP(
    const __bf16* __restrict__ A, const __bf16* __restrict__ Bm,
    const float* __restrict__ bias, void* __restrict__ outP,
    int NT, int N, int K) {
  __shared__ __align__(16) char SM[32768];
  const int tid = threadIdx.x;
  const int lane = tid & 63;
  const int wave = tid >> 6;
  const int wr = (wave >> 1) * 64, wc = (wave & 1) * 64;
  const int l15 = lane & 15, l4 = lane >> 4;

  const int cpx = (int)gridDim.x >> 3;
  const int wg = ((int)blockIdx.x & 7) * cpx + ((int)blockIdx.x >> 3);
  const int m0 = (wg / NT) * 128, n0 = (wg % NT) * 128;

  f32x4 acc[4][4];
#pragma unroll
  for (int i = 0; i < 4; ++i)
#pragma unroll
    for (int j = 0; j < 4; ++j) acc[i][j] = (f32x4){0.f, 0.f, 0.f, 0.f};

  const int phys = lane & 3;
  const int row0 = wave * 16 + (lane >> 2);
  const int row1 = row0 + 64;
  const int orig0 = (phys - (row0 >> 1)) & 3;
  const int orig1 = (phys - (row1 >> 1)) & 3;
  const size_t rs = (size_t)K * 2;
  const char* a0 = (const char*)A + (size_t)(m0 + row0) * rs + orig0 * 16;
  const char* a1 = (const char*)A + (size_t)(m0 + row1) * rs + orig1 * 16;
  const char* b0 = (const char*)Bm + (size_t)(n0 + row0) * rs + orig0 * 16;
  const char* b1 = (const char*)Bm + (size_t)(n0 + row1) * rs + orig1 * 16;

#define STAGEP(tt, bufb) do { \
    GLD16(a0 + (size_t)(tt) * 64, SM + (bufb) + wave * 1024); \
    GLD16(a1 + (size_t)(tt) * 64, SM + (bufb) + 4096 + wave * 1024); \
    GLD16(b0 + (size_t)(tt) * 64, SM + (bufb) + 8192 + wave * 1024); \
    GLD16(b1 + (size_t)(tt) * 64, SM + (bufb) + 12288 + wave * 1024); \
  } while (0)

  const int KT = K >> 5;
  STAGEP(0, 0);
  for (int t = 0; t < KT; ++t) {
    const int cb = (t & 1) << 14;
    if (t + 1 < KT) {
      STAGEP(t + 1, cb ^ 16384);
      asm volatile("s_waitcnt vmcnt(4)" ::: "memory");
    } else {
      asm volatile("s_waitcnt vmcnt(0)" ::: "memory");
    }
    __builtin_amdgcn_s_barrier();
    asm volatile("" ::: "memory");
    bf16x8 af[4], bfr[4];
#pragma unroll
    for (int mi = 0; mi < 4; ++mi) {
      const int arow = wr + mi * 16 + l15;
      af[mi] = *(const bf16x8*)(SM + cb + arow * 64 + (((l4 + (arow >> 1)) & 3) << 4));
    }
#pragma unroll
    for (int ni = 0; ni < 4; ++ni) {
      const int brow = wc + ni * 16 + l15;
      bfr[ni] = *(const bf16x8*)(SM + cb + 8192 + brow * 64 + (((l4 + (brow >> 1)) & 3) << 4));
    }
    asm volatile("s_waitcnt lgkmcnt(0)" ::: "memory");
    __builtin_amdgcn_sched_barrier(0);
    __builtin_amdgcn_s_setprio(1);
#pragma unroll
    for (int mi = 0; mi < 4; ++mi)
#pragma unroll
      for (int ni = 0; ni < 4; ++ni)
        acc[mi][ni] = __builtin_amdgcn_mfma_f32_16x16x32_bf16(af[mi], bfr[ni], acc[mi][ni], 0, 0, 0);
    __builtin_amdgcn_s_setprio(0);
    __builtin_amdgcn_s_barrier();
    asm volatile("" ::: "memory");
  }
#undef STAGEP

#pragma unroll
  for (int ni = 0; ni < 4; ++ni) {
    int n = n0 + wc + ni * 16 + l15;
    float bv = bias[n];
#pragma unroll
    for (int mi = 0; mi < 4; ++mi) {
#pragma unroll
      for (int r = 0; r < 4; ++r) {
        int m = m0 + wr + mi * 16 + l4 * 4 + r;
        float v = acc[mi][ni][r] + bv;
        if (GELU) v = gelu_f(v);
        if (OUT8) {
          unsigned int u = __builtin_amdgcn_cvt_pk_fp8_f32(v, v, 0, 0);
          ((unsigned char*)outP)[(size_t)m * N + n] = (unsigned char)u;
        } else {
          ((__bf16*)outP)[(size_t)m * N + n] = (__bf16)v;
        }
      }
    }
  }
}

// -------- lm-head fp8 GEMM: 128x128 tile, BK=64 (64B rows), double-buffered 32KB,
// 16-B-pair rotation layout (2-way banks = free), counted vmcnt(4), fused softmax
// partials + LDS-restaged f32 stores.
__global__ __launch_bounds__(256, 4) void gemmLM8(
    const unsigned char* __restrict__ A, const unsigned char* __restrict__ Bm,
    float* __restrict__ outF, float* __restrict__ pm, float* __restrict__ ps) {
  __shared__ __align__(16) char SM[32768];
  const int tid = threadIdx.x;
  const int lane = tid & 63;
  const int wave = tid >> 6;
  const int wr = (wave >> 1) * 64, wc = (wave & 1) * 64;
  const int l15 = lane & 15, l4 = lane >> 4;

  const int cpx = (int)gridDim.x >> 3;
  const int wg = ((int)blockIdx.x & 7) * cpx + ((int)blockIdx.x >> 3);
  const int m0 = (wg >> 4) * 128, n0 = (wg & 15) * 128;

  f32x4 acc[4][4];
#pragma unroll
  for (int i = 0; i < 4; ++i)
#pragma unroll
    for (int j = 0; j < 4; ++j) acc[i][j] = (f32x4){0.f, 0.f, 0.f, 0.f};

  // staging: rows of 64 B (64 k), phys pair = (pair + (row>>1)) & 3
  const int ppair = lane & 3;
  const int row0 = wave * 16 + (lane >> 2);
  const int row1 = row0 + 64;
  const int og0 = (ppair - (row0 >> 1)) & 3;
  const int og1 = (ppair - (row1 >> 1)) & 3;
  const unsigned char* a0 = A + (size_t)(m0 + row0) * DSZ + og0 * 16;
  const unsigned char* a1 = A + (size_t)(m0 + row1) * DSZ + og1 * 16;
  const unsigned char* b0 = Bm + (size_t)(n0 + row0) * DSZ + og0 * 16;
  const unsigned char* b1 = Bm + (size_t)(n0 + row1) * DSZ + og1 * 16;

#define STG8(tt, bufb) do { \
    GLD16(a0 + (size_t)(tt) * 64, SM + (bufb) + wave * 1024); \
    GLD16(a1 + (size_t)(tt) * 64, SM + (bufb) + 4096 + wave * 1024); \
    GLD16(b0 + (size_t)(tt) * 64, SM + (bufb) + 8192 + wave * 1024); \
    GLD16(b1 + (size_t)(tt) * 64, SM + (bufb) + 12288 + wave * 1024); \
  } while (0)

  STG8(0, 0);
  for (int t = 0; t < 16; ++t) {
    const int cb = (t & 1) << 14;
    if (t < 15) {
      STG8(t + 1, cb ^ 16384);
      asm volatile("s_waitcnt vmcnt(4)" ::: "memory");
    } else {
      asm volatile("s_waitcnt vmcnt(0)" ::: "memory");
    }
    __builtin_amdgcn_s_barrier();
    asm volatile("" ::: "memory");
    long af[4][2], bfr[4][2];
#pragma unroll
    for (int mi = 0; mi < 4; ++mi) {
      const int row = wr + mi * 16 + l15;
#pragma unroll
      for (int kk = 0; kk < 2; ++kk) {
        const int ph = ((kk * 2 + (l4 >> 1)) + (row >> 1)) & 3;
        af[mi][kk] = *(const long*)(SM + cb + row * 64 + ph * 16 + (l4 & 1) * 8);
      }
    }
#pragma unroll
    for (int ni = 0; ni < 4; ++ni) {
      const int row = wc + ni * 16 + l15;
#pragma unroll
      for (int kk = 0; kk < 2; ++kk) {
        const int ph = ((kk * 2 + (l4 >> 1)) + (row >> 1)) & 3;
        bfr[ni][kk] = *(const long*)(SM + cb + 8192 + row * 64 + ph * 16 + (l4 & 1) * 8);
      }
    }
    asm volatile("s_waitcnt lgkmcnt(0)" ::: "memory");
    __builtin_amdgcn_sched_barrier(0);
    __builtin_amdgcn_s_setprio(1);
#pragma unroll
    for (int kk = 0; kk < 2; ++kk)
#pragma unroll
      for (int mi = 0; mi < 4; ++mi)
#pragma unroll
        for (int ni = 0; ni < 4; ++ni)
          acc[mi][ni] = __builtin_amdgcn_mfma_f32_16x16x32_fp8_fp8(
              af[mi][kk], bfr[ni][kk], acc[mi][ni], 0, 0, 0);
    __builtin_amdgcn_s_setprio(0);
    __builtin_amdgcn_s_barrier();
    asm volatile("" ::: "memory");
  }
#undef STG8

  // ---- fused softmax partials per 64-v stripe
  const int ch = (m0 + wr) >> 6;
#pragma unroll
  for (int ni = 0; ni < 4; ++ni) {
    int n = n0 + wc + ni * 16 + l15;   // pos = b*T + t
    float mloc = -1e30f, sloc = 0.f;
#pragma unroll
    for (int mi = 0; mi < 4; ++mi) {
      int vbase = m0 + wr + mi * 16 + l4 * 4;
#pragma unroll
      for (int r = 0; r < 4; ++r)
        if (vbase + r < VSZ) mloc = fmaxf(mloc, acc[mi][ni][r]);
    }
#pragma unroll
    for (int mi = 0; mi < 4; ++mi) {
      int vbase = m0 + wr + mi * 16 + l4 * 4;
#pragma unroll
      for (int r = 0; r < 4; ++r)
        if (vbase + r < VSZ) sloc += __expf(acc[mi][ni][r] - mloc);
    }
#pragma unroll
    for (int off = 16; off <= 32; off <<= 1) {
      float mo = __shfl_xor(mloc, off, 64);
      float so = __shfl_xor(sloc, off, 64);
      float nm = fmaxf(mloc, mo);
      sloc = sloc * __expf(mloc - nm) + so * __expf(mo - nm);
      mloc = nm;
    }
    if (l4 == 0) {
      pm[(size_t)ch * NPOS + n] = mloc;
      ps[(size_t)ch * NPOS + n] = sloc;
    }
  }

  // ---- LDS-restaged aligned f32 stores: 4 quarters of 32 v-rows x 128 t
  float* epi = (float*)SM;                 // [32][132] = 16.9 KB
  const int bb = n0 >> 9, t0 = n0 & 511;
  float* outG = outF + 1 + (size_t)bb * VSZ * TSZ + t0;
  const int trow = tid >> 5;
  const int lofs = (tid & 31) * 4;
#pragma unroll
  for (int q = 0; q < 4; ++q) {
    __builtin_amdgcn_s_barrier();
    asm volatile("" ::: "memory");
    if ((wave >> 1) == (q >> 1)) {
      const int miBase = (q & 1) * 2;
#pragma unroll
      for (int mi2 = 0; mi2 < 2; ++mi2)
#pragma unroll
        for (int ni = 0; ni < 4; ++ni)
#pragma unroll
          for (int r = 0; r < 4; ++r)
            epi[(mi2 * 16 + l4 * 4 + r) * 132 + wc + ni * 16 + l15] =
                acc[miBase + mi2][ni][r];
    }
    __builtin_amdgcn_s_barrier();
    asm volatile("" ::: "memory");
#pragma unroll
    for (int p = 0; p < 4; ++p) {
      int row = p * 8 + trow;
      int v = m0 + q * 32 + row;
      if (v < VSZ) {
        f32x4 val = *(const f32x4*)&epi[row * 132 + lofs];
        float* gp = outG + (size_t)v * TSZ + lofs;
        gp[0] = val[0]; gp[1] = val[1]; gp[2] = val[2]; gp[3] = val[3];
      }
    }
  }
}

// -------- merge softmax partials per position (4 independent chains; 788 = 4*197)
__global__ __launch_bounds__(256) void lsemerge_kernel(const float* __restrict__ pm,
                                                       const float* __restrict__ ps,
                                                       const float* __restrict__ outF,
                                                       const int* __restrict__ labels,
                                                       float* __restrict__ contrib) {
  int pos = blockIdx.x * 256 + threadIdx.x;
  float m[4] = {-1e30f, -1e30f, -1e30f, -1e30f};
  float s[4] = {0.f, 0.f, 0.f, 0.f};
  for (int c = 0; c < NCH; c += 4) {
#pragma unroll
    for (int j = 0; j < 4; ++j) {
      float cm = pm[(size_t)(c + j) * NPOS + pos];
      float cs = ps[(size_t)(c + j) * NPOS + pos];
      float nm = fmaxf(m[j], cm);
      s[j] = s[j] * __expf(m[j] - nm) + cs * __expf(cm - nm);
      m[j] = nm;
    }
  }
#pragma unroll
  for (int j = 1; j < 4; ++j) {
    float nm = fmaxf(m[0], m[j]);
    s[0] = s[0] * __expf(m[0] - nm) + s[j] * __expf(m[j] - nm);
    m[0] = nm;
  }
  float lse = m[0] + logf(s[0]);
  int b = pos >> 9, t = pos & 511;
  int lab = labels[pos];
  float x = outF[1 + (size_t)b * VSZ * TSZ + (size_t)lab * TSZ + t];
  contrib[pos] = lse - x;
}

__global__ __launch_bounds__(256) void lossfinal_kernel(const float* __restrict__ contrib,
                                                        float* __restrict__ dout) {
  __shared__ float red[256];
  int tid = threadIdx.x;
  float a = 0.f;
  for (int i = tid; i < NPOS; i += 256) a += contrib[i];
  red[tid] = a;
  __syncthreads();
  for (int off = 128; off; off >>= 1) {
    if (tid < off) red[tid] += red[tid + off];
    __syncthreads();
  }
  if (tid == 0) dout[0] = red[0] / (float)NPOS;
}

extern "C" void kernel_launch(void* const* d_in, const int* in_sizes, int n_in,
                              void* d_out, int out_size, void* d_ws, size_t ws_size,
                              hipStream_t stream) {
  const int* input_ids = (const int*)d_in[0];
  const int* labels    = (const int*)d_in[1];
  const float* wte     = (const float*)d_in[2];
  const float* enc_w1  = (const float*)d_in[3];
  const float* enc_b1  = (const float*)d_in[4];
  const float* enc_w2  = (const float*)d_in[5];
  const float* enc_b2  = (const float*)d_in[6];
  const float* proj_w  = (const float*)d_in[7];
  const float* proj_b  = (const float*)d_in[8];
  const float* dec_w1  = (const float*)d_in[9];
  const float* dec_b1  = (const float*)d_in[10];
  const float* dec_w2  = (const float*)d_in[11];
  const float* dec_b2  = (const float*)d_in[12];
  const float* lm_w    = (const float*)d_in[13];
  float* outF = (float*)d_out;

  char* w = (char*)d_ws;
  size_t off = 0;
  unsigned char* lm8 = (unsigned char*)(w + off); off += (size_t)VPAD * DSZ;  // 51.6 MB
  __bf16* w1T   = (__bf16*)(w + off); off += (size_t)HSZ * DSZ * 2;       // 8 MB
  __bf16* w2T   = (__bf16*)(w + off); off += (size_t)DSZ * HSZ * 2;       // 8 MB
  __bf16* projT = (__bf16*)(w + off); off += (size_t)DSZ * 512 * 2;       // 1 MB
  __bf16* win   = (__bf16*)(w + off); off += (size_t)2048 * 512 * 2;      // 2 MB
  __bf16* pbuf  = (__bf16*)(w + off); off += (size_t)2048 * DSZ * 2;      // 4 MB
  __bf16* abuf  = (__bf16*)(w + off); off += (size_t)2048 * HSZ * 2;      // 16 MB
  unsigned char* dbuf8 = (unsigned char*)(w + off); off += (size_t)2048 * DSZ;  // 2 MB
  float* e      = (float*)(w + off);  off += (size_t)BSZ * DSZ * 4;
  float* t1p    = (float*)(w + off);  off += (size_t)BSZ * KS1 * HSZ * 4;
  float* ep     = (float*)(w + off);  off += (size_t)BSZ * KS2 * DSZ * 4;
  float* contrib= (float*)(w + off);  off += (size_t)NPOS * 4;
  // softmax partials alias abuf (free after dec2): 788*2048*4*2 = 12.9 MB <= 16 MB
  float* pm = (float*)abuf;
  float* ps = pm + (size_t)NCH * NPOS;
  (void)ws_size; (void)in_sizes; (void)n_in; (void)out_size;

  // all weight transposes in one dispatch (lmT -> fp8)
  transpose_all<<<14784, 256, 0, stream>>>(lm_w, dec_w1, dec_w2, proj_w, lm8, w1T, w2T, projT);

  // encoder on last token only (K-split for parallelism)
  enc1p_kernel<<<dim3(BSZ, HSZ / 256, KS1), 256, 0, stream>>>(input_ids, wte, enc_w1, t1p);
  enc2p_kernel<<<dim3(BSZ, DSZ / 256, KS2), 256, 0, stream>>>(t1p, enc_b1, enc_w2, ep);
  enc2c_kernel<<<dim3(BSZ * DSZ / 256), 256, 0, stream>>>(ep, enc_b2, e);
  win_kernel<<<2048, 256, 0, stream>>>(e, win);

  // GEMM chain (1D grids, all divisible by 8 for the XCD swizzle)
  gemmP<0, 0><<<128, 256, 0, stream>>>(win, projT, proj_b, pbuf, 8, DSZ, 512);
  gemmP<1, 0><<<512, 256, 0, stream>>>(pbuf, w1T, dec_b1, abuf, 32, HSZ, DSZ);
  gemmP<0, 1><<<128, 256, 0, stream>>>(abuf, w2T, dec_b2, dbuf8, 8, DSZ, HSZ);
  // lm head fp8: 394 m-tiles x 16 n-tiles = 6304 blocks
  gemmLM8<<<6304, 256, 0, stream>>>(lm8, dbuf8, outF, pm, ps);

  // loss: merge partials + mean
  lsemerge_kernel<<<dim3(NPOS / 256), 256, 0, stream>>>(pm, ps, outF, labels, contrib);
  lossfinal_kernel<<<1, 256, 0, stream>>>(contrib, outF);
}

// Round 8
// 538.993 us; speedup vs baseline: 1.4154x; 1.0177x over previous
//
#include <hip/hip_runtime.h>

#define VSZ 50257
#define DSZ 1024
#define TSZ 512
#define BSZ 4
#define HSZ 4096
#define VPAD 50432   // 394*128
#define NCH (VPAD / 64)   // 788 v-stripes of 64
#define NPOS 2048
#define QS 16.0f
#define DQS (1.0f / 256.0f)

typedef __attribute__((ext_vector_type(4))) float f32x4;

#define GLD16(gp, lp) __builtin_amdgcn_global_load_lds( \
  (const __attribute__((address_space(1))) unsigned int*)(gp), \
  (__attribute__((address_space(3))) unsigned int*)(lp), 16, 0, 0)

__device__ __forceinline__ float gelu_f(float x) {
  float x3 = x * x * x;
  float u = 0.7978845608028654f * (x + 0.044715f * x3);
  return 0.5f * x * (1.f + tanhf(u));
}

__device__ __forceinline__ unsigned char q8(float v) {
  return (unsigned char)__builtin_amdgcn_cvt_pk_fp8_f32(v * QS, v * QS, 0, 0);
}

// -------- all weight transposes fused: f32 (R x C) -> fp8 x16 (Cpad x R), 64x64 tiles
__global__ __launch_bounds__(256) void transpose_all(
    const float* __restrict__ lm_w, const float* __restrict__ dw1,
    const float* __restrict__ dw2, const float* __restrict__ pw,
    unsigned char* __restrict__ lm8, unsigned char* __restrict__ w18,
    unsigned char* __restrict__ w28, unsigned char* __restrict__ p8) {
  __shared__ float tile[64][65];
  int bid = blockIdx.x;
  const float* src; unsigned char* dst; int R, C, Cpad, bx, by;
  if (bid < 12608)      { src = lm_w; dst = lm8; R = DSZ; C = VSZ; Cpad = VPAD; bx = bid % 788; by = bid / 788; }
  else if (bid < 13632) { int b = bid - 12608; src = dw1; dst = w18; R = DSZ; C = HSZ; Cpad = HSZ; bx = b % 64; by = b / 64; }
  else if (bid < 14656) { int b = bid - 13632; src = dw2; dst = w28; R = HSZ; C = DSZ; Cpad = DSZ; bx = b % 16; by = b / 16; }
  else                  { int b = bid - 14656; src = pw;  dst = p8;  R = 512; C = DSZ; Cpad = DSZ; bx = b % 16; by = b / 16; }
  int c0 = bx * 64, r0 = by * 64;
  int tid = threadIdx.x;
  int wv = tid >> 6, ln = tid & 63;
  int c = c0 + ln;
#pragma unroll 4
  for (int i = 0; i < 16; ++i) {
    int r = i * 4 + wv;
    tile[r][ln] = (c < C) ? src[(size_t)(r0 + r) * C + c] : 0.f;
  }
  __syncthreads();
  int ccb = tid >> 4;
  int r4 = (tid & 15) * 4;
#pragma unroll
  for (int j = 0; j < 4; ++j) {
    int cc = ccb + j * 16;
    if (c0 + cc >= Cpad) continue;
    unsigned int u = __builtin_amdgcn_cvt_pk_fp8_f32(QS * tile[r4 + 0][cc], QS * tile[r4 + 1][cc], 0, 0);
    u = __builtin_amdgcn_cvt_pk_fp8_f32(QS * tile[r4 + 2][cc], QS * tile[r4 + 3][cc], u, 1);
    *(unsigned int*)(dst + (size_t)(c0 + cc) * R + r0 + r4) = u;
  }
}

// -------- encoder layer 1 partials: K-split dot over d-chunk of 128
#define KS1 8
__global__ __launch_bounds__(256) void enc1p_kernel(const int* __restrict__ ids,
                                                    const float* __restrict__ wte,
                                                    const float* __restrict__ w1,
                                                    float* __restrict__ t1p) {
  int b = blockIdx.x;
  int h = blockIdx.y * 256 + threadIdx.x;
  int kc = blockIdx.z;
  int tok = ids[b * TSZ + (TSZ - 1)];
  const float* ev = wte + (size_t)tok * DSZ + kc * (DSZ / KS1);
  const float* w = w1 + (size_t)kc * (DSZ / KS1) * HSZ + h;
  float s = 0.f;
#pragma unroll 4
  for (int d = 0; d < DSZ / KS1; ++d) s += ev[d] * w[(size_t)d * HSZ];
  t1p[((size_t)(b * KS1 + kc)) * HSZ + h] = s;
}

// -------- encoder layer 2 partials (enc1 combine + gelu fused in):
#define KS2 16
__global__ __launch_bounds__(256) void enc2p_kernel(const float* __restrict__ t1p,
                                                    const float* __restrict__ b1,
                                                    const float* __restrict__ w2,
                                                    float* __restrict__ ep) {
  __shared__ float ts[256];
  int b = blockIdx.x;
  int i = blockIdx.y * 256 + threadIdx.x;
  int kc = blockIdx.z;
  int h = kc * 256 + threadIdx.x;
  float s0 = b1[h];
#pragma unroll
  for (int cc = 0; cc < KS1; ++cc) s0 += t1p[((size_t)(b * KS1 + cc)) * HSZ + h];
  ts[threadIdx.x] = gelu_f(s0);
  __syncthreads();
  const float* w = w2 + (size_t)kc * 256 * DSZ + i;
  float s = 0.f;
#pragma unroll 4
  for (int j = 0; j < 256; ++j) s += ts[j] * w[(size_t)j * DSZ];
  ep[((size_t)(b * KS2 + kc)) * DSZ + i] = s;
}

__global__ __launch_bounds__(256) void enc2c_kernel(const float* __restrict__ ep,
                                                    const float* __restrict__ b2,
                                                    float* __restrict__ e) {
  int idx = blockIdx.x * 256 + threadIdx.x;
  int b = idx >> 10, i = idx & (DSZ - 1);
  float s = b2[i];
#pragma unroll
  for (int kc = 0; kc < KS2; ++kc) s += ep[((size_t)(b * KS2 + kc)) * DSZ + i];
  e[idx] = s;
}

// -------- windows: win8[b*T+t][j] = fp8(e[b][t+j] * 16)
__global__ void win8_kernel(const float* __restrict__ e, unsigned char* __restrict__ win8) {
  int blk = blockIdx.x;
  int b = blk >> 9, t = blk & 511;
  const float* eb = e + b * DSZ;
  for (int j = threadIdx.x; j < 512; j += 256)
    win8[(size_t)blk * 512 + j] = q8(eb[t + j]);
}

// -------- unified fp8 GEMM: C[m][n] = (1/256) sum_k A8[m][k]*B8[n][k]
// 128x128 tile, BK=64 (64B rows) double-buffered 32KB LDS (4 blocks/CU),
// 16B-pair rotation layout (2-way banks = free), counted vmcnt(4).
// MODE 0: +bias, opt gelu, out fp8 x16 row-major [M][N].
// MODE 1: lm head: fused softmax partials + LDS-restaged f32 stores.
template<int GELU, int MODE>
__global__ __launch_bounds__(256, 4) void gemm8(
    const unsigned char* __restrict__ A, const unsigned char* __restrict__ Bm,
    const float* __restrict__ bias, unsigned char* __restrict__ out8,
    float* __restrict__ outF, float* __restrict__ pm, float* __restrict__ ps,
    int NT, int N, int K) {
  __shared__ __align__(16) char SM[32768];
  const int tid = threadIdx.x;
  const int lane = tid & 63;
  const int wave = tid >> 6;
  const int wr = (wave >> 1) * 64, wc = (wave & 1) * 64;
  const int l15 = lane & 15, l4 = lane >> 4;

  const int cpx = (int)gridDim.x >> 3;
  const int wg = ((int)blockIdx.x & 7) * cpx + ((int)blockIdx.x >> 3);
  const int m0 = (wg / NT) * 128, n0 = (wg % NT) * 128;

  f32x4 acc[4][4];
#pragma unroll
  for (int i = 0; i < 4; ++i)
#pragma unroll
    for (int j = 0; j < 4; ++j) acc[i][j] = (f32x4){0.f, 0.f, 0.f, 0.f};

  // staging: rows of 64 B (64 k), phys 16B-pair = (pair + (row>>1)) & 3
  const int ppair = lane & 3;
  const int row0 = wave * 16 + (lane >> 2);
  const int row1 = row0 + 64;
  const int og0 = (ppair - (row0 >> 1)) & 3;
  const int og1 = (ppair - (row1 >> 1)) & 3;
  const unsigned char* a0 = A + (size_t)(m0 + row0) * K + og0 * 16;
  const unsigned char* a1 = A + (size_t)(m0 + row1) * K + og1 * 16;
  const unsigned char* b0 = Bm + (size_t)(n0 + row0) * K + og0 * 16;
  const unsigned char* b1 = Bm + (size_t)(n0 + row1) * K + og1 * 16;

#define STG8(tt, bufb) do { \
    GLD16(a0 + (size_t)(tt) * 64, SM + (bufb) + wave * 1024); \
    GLD16(a1 + (size_t)(tt) * 64, SM + (bufb) + 4096 + wave * 1024); \
    GLD16(b0 + (size_t)(tt) * 64, SM + (bufb) + 8192 + wave * 1024); \
    GLD16(b1 + (size_t)(tt) * 64, SM + (bufb) + 12288 + wave * 1024); \
  } while (0)

  const int KT = K >> 6;
  STG8(0, 0);
  for (int t = 0; t < KT; ++t) {
    const int cb = (t & 1) << 14;
    if (t + 1 < KT) {
      STG8(t + 1, cb ^ 16384);
      asm volatile("s_waitcnt vmcnt(4)" ::: "memory");
    } else {
      asm volatile("s_waitcnt vmcnt(0)" ::: "memory");
    }
    __builtin_amdgcn_s_barrier();
    asm volatile("" ::: "memory");
    long af[4][2], bfr[4][2];
#pragma unroll
    for (int mi = 0; mi < 4; ++mi) {
      const int row = wr + mi * 16 + l15;
#pragma unroll
      for (int kk = 0; kk < 2; ++kk) {
        const int ph = ((kk * 2 + (l4 >> 1)) + (row >> 1)) & 3;
        af[mi][kk] = *(const long*)(SM + cb + row * 64 + ph * 16 + (l4 & 1) * 8);
      }
    }
#pragma unroll
    for (int ni = 0; ni < 4; ++ni) {
      const int row = wc + ni * 16 + l15;
#pragma unroll
      for (int kk = 0; kk < 2; ++kk) {
        const int ph = ((kk * 2 + (l4 >> 1)) + (row >> 1)) & 3;
        bfr[ni][kk] = *(const long*)(SM + cb + 8192 + row * 64 + ph * 16 + (l4 & 1) * 8);
      }
    }
    asm volatile("s_waitcnt lgkmcnt(0)" ::: "memory");
    __builtin_amdgcn_sched_barrier(0);
    __builtin_amdgcn_s_setprio(1);
#pragma unroll
    for (int kk = 0; kk < 2; ++kk)
#pragma unroll
      for (int mi = 0; mi < 4; ++mi)
#pragma unroll
        for (int ni = 0; ni < 4; ++ni)
          acc[mi][ni] = __builtin_amdgcn_mfma_f32_16x16x32_fp8_fp8(
              af[mi][kk], bfr[ni][kk], acc[mi][ni], 0, 0, 0);
    __builtin_amdgcn_s_setprio(0);
    __builtin_amdgcn_s_barrier();
    asm volatile("" ::: "memory");
  }
#undef STG8

  if (MODE == 0) {
#pragma unroll
    for (int ni = 0; ni < 4; ++ni) {
      int n = n0 + wc + ni * 16 + l15;
      float bv = bias[n];
#pragma unroll
      for (int mi = 0; mi < 4; ++mi) {
#pragma unroll
        for (int r = 0; r < 4; ++r) {
          int m = m0 + wr + mi * 16 + l4 * 4 + r;
          float v = acc[mi][ni][r] * DQS + bv;
          if (GELU) v = gelu_f(v);
          out8[(size_t)m * N + n] = q8(v);
        }
      }
    }
  } else {
    // dequantize accumulators to true logits
#pragma unroll
    for (int i = 0; i < 4; ++i)
#pragma unroll
      for (int j = 0; j < 4; ++j)
#pragma unroll
        for (int r = 0; r < 4; ++r) acc[i][j][r] *= DQS;

    // ---- fused softmax partials per 64-v stripe
    const int ch = (m0 + wr) >> 6;
#pragma unroll
    for (int ni = 0; ni < 4; ++ni) {
      int n = n0 + wc + ni * 16 + l15;   // pos = b*T + t
      float mloc = -1e30f, sloc = 0.f;
#pragma unroll
      for (int mi = 0; mi < 4; ++mi) {
        int vbase = m0 + wr + mi * 16 + l4 * 4;
#pragma unroll
        for (int r = 0; r < 4; ++r)
          if (vbase + r < VSZ) mloc = fmaxf(mloc, acc[mi][ni][r]);
      }
#pragma unroll
      for (int mi = 0; mi < 4; ++mi) {
        int vbase = m0 + wr + mi * 16 + l4 * 4;
#pragma unroll
        for (int r = 0; r < 4; ++r)
          if (vbase + r < VSZ) sloc += __expf(acc[mi][ni][r] - mloc);
      }
#pragma unroll
      for (int off = 16; off <= 32; off <<= 1) {
        float mo = __shfl_xor(mloc, off, 64);
        float so = __shfl_xor(sloc, off, 64);
        float nm = fmaxf(mloc, mo);
        sloc = sloc * __expf(mloc - nm) + so * __expf(mo - nm);
        mloc = nm;
      }
      if (l4 == 0) {
        pm[(size_t)ch * NPOS + n] = mloc;
        ps[(size_t)ch * NPOS + n] = sloc;
      }
    }

    // ---- LDS-restaged aligned f32 stores: 4 quarters of 32 v-rows x 128 t
    float* epi = (float*)SM;                 // [32][132] = 16.9 KB
    const int bb = n0 >> 9, t0 = n0 & 511;
    float* outG = outF + 1 + (size_t)bb * VSZ * TSZ + t0;
    const int trow = tid >> 5;
    const int lofs = (tid & 31) * 4;
#pragma unroll
    for (int q = 0; q < 4; ++q) {
      __builtin_amdgcn_s_barrier();
      asm volatile("" ::: "memory");
      if ((wave >> 1) == (q >> 1)) {
        const int miBase = (q & 1) * 2;
#pragma unroll
        for (int mi2 = 0; mi2 < 2; ++mi2)
#pragma unroll
          for (int ni = 0; ni < 4; ++ni)
#pragma unroll
            for (int r = 0; r < 4; ++r)
              epi[(mi2 * 16 + l4 * 4 + r) * 132 + wc + ni * 16 + l15] =
                  acc[miBase + mi2][ni][r];
      }
      __builtin_amdgcn_s_barrier();
      asm volatile("" ::: "memory");
#pragma unroll
      for (int p = 0; p < 4; ++p) {
        int row = p * 8 + trow;
        int v = m0 + q * 32 + row;
        if (v < VSZ) {
          f32x4 val = *(const f32x4*)&epi[row * 132 + lofs];
          float* gp = outG + (size_t)v * TSZ + lofs;
          gp[0] = val[0]; gp[1] = val[1]; gp[2] = val[2]; gp[3] = val[3];
        }
      }
    }
  }
}

// -------- merge softmax partials per position (4 independent chains; 788 = 4*197)
__global__ __launch_bounds__(256) void lsemerge_kernel(const float* __restrict__ pm,
                                                       const float* __restrict__ ps,
                                                       const float* __restrict__ outF,
                                                       const int* __restrict__ labels,
                                                       float* __restrict__ contrib) {
  int pos = blockIdx.x * 256 + threadIdx.x;
  float m[4] = {-1e30f, -1e30f, -1e30f, -1e30f};
  float s[4] = {0.f, 0.f, 0.f, 0.f};
  for (int c = 0; c < NCH; c += 4) {
#pragma unroll
    for (int j = 0; j < 4; ++j) {
      float cm = pm[(size_t)(c + j) * NPOS + pos];
      float cs = ps[(size_t)(c + j) * NPOS + pos];
      float nm = fmaxf(m[j], cm);
      s[j] = s[j] * __expf(m[j] - nm) + cs * __expf(cm - nm);
      m[j] = nm;
    }
  }
#pragma unroll
  for (int j = 1; j < 4; ++j) {
    float nm = fmaxf(m[0], m[j]);
    s[0] = s[0] * __expf(m[0] - nm) + s[j] * __expf(m[j] - nm);
    m[0] = nm;
  }
  float lse = m[0] + logf(s[0]);
  int b = pos >> 9, t = pos & 511;
  int lab = labels[pos];
  float x = outF[1 + (size_t)b * VSZ * TSZ + (size_t)lab * TSZ + t];
  contrib[pos] = lse - x;
}

__global__ __launch_bounds__(256) void lossfinal_kernel(const float* __restrict__ contrib,
                                                        float* __restrict__ dout) {
  __shared__ float red[256];
  int tid = threadIdx.x;
  float a = 0.f;
  for (int i = tid; i < NPOS; i += 256) a += contrib[i];
  red[tid] = a;
  __syncthreads();
  for (int off = 128; off; off >>= 1) {
    if (tid < off) red[tid] += red[tid + off];
    __syncthreads();
  }
  if (tid == 0) dout[0] = red[0] / (float)NPOS;
}

extern "C" void kernel_launch(void* const* d_in, const int* in_sizes, int n_in,
                              void* d_out, int out_size, void* d_ws, size_t ws_size,
                              hipStream_t stream) {
  const int* input_ids = (const int*)d_in[0];
  const int* labels    = (const int*)d_in[1];
  const float* wte     = (const float*)d_in[2];
  const float* enc_w1  = (const float*)d_in[3];
  const float* enc_b1  = (const float*)d_in[4];
  const float* enc_w2  = (const float*)d_in[5];
  const float* enc_b2  = (const float*)d_in[6];
  const float* proj_w  = (const float*)d_in[7];
  const float* proj_b  = (const float*)d_in[8];
  const float* dec_w1  = (const float*)d_in[9];
  const float* dec_b1  = (const float*)d_in[10];
  const float* dec_w2  = (const float*)d_in[11];
  const float* dec_b2  = (const float*)d_in[12];
  const float* lm_w    = (const float*)d_in[13];
  float* outF = (float*)d_out;

  char* w = (char*)d_ws;
  size_t off = 0;
  unsigned char* lm8  = (unsigned char*)(w + off); off += (size_t)VPAD * DSZ;   // 51.6 MB
  unsigned char* w18  = (unsigned char*)(w + off); off += (size_t)HSZ * DSZ;    // 4 MB
  unsigned char* w28  = (unsigned char*)(w + off); off += (size_t)DSZ * HSZ;    // 4 MB
  unsigned char* p8   = (unsigned char*)(w + off); off += (size_t)DSZ * 512;    // 0.5 MB
  unsigned char* win8 = (unsigned char*)(w + off); off += (size_t)NPOS * 512;   // 1 MB
  unsigned char* pbuf8= (unsigned char*)(w + off); off += (size_t)NPOS * DSZ;   // 2 MB
  unsigned char* abuf8= (unsigned char*)(w + off); off += (size_t)NPOS * HSZ;   // 8 MB
  unsigned char* dbuf8= (unsigned char*)(w + off); off += (size_t)NPOS * DSZ;   // 2 MB
  float* e      = (float*)(w + off);  off += (size_t)BSZ * DSZ * 4;
  float* t1p    = (float*)(w + off);  off += (size_t)BSZ * KS1 * HSZ * 4;
  float* ep     = (float*)(w + off);  off += (size_t)BSZ * KS2 * DSZ * 4;
  float* contrib= (float*)(w + off);  off += (size_t)NPOS * 4;
  float* pm     = (float*)(w + off);  off += (size_t)NCH * NPOS * 4;            // 6.5 MB
  float* ps     = (float*)(w + off);  off += (size_t)NCH * NPOS * 4;            // 6.5 MB
  (void)ws_size; (void)in_sizes; (void)n_in; (void)out_size;

  // all weight transposes in one dispatch (all -> fp8 x16)
  transpose_all<<<14784, 256, 0, stream>>>(lm_w, dec_w1, dec_w2, proj_w, lm8, w18, w28, p8);

  // encoder on last token only (K-split for parallelism)
  enc1p_kernel<<<dim3(BSZ, HSZ / 256, KS1), 256, 0, stream>>>(input_ids, wte, enc_w1, t1p);
  enc2p_kernel<<<dim3(BSZ, DSZ / 256, KS2), 256, 0, stream>>>(t1p, enc_b1, enc_w2, ep);
  enc2c_kernel<<<dim3(BSZ * DSZ / 256), 256, 0, stream>>>(ep, enc_b2, e);
  win8_kernel<<<2048, 256, 0, stream>>>(e, win8);

  // fp8 GEMM chain (1D grids, all divisible by 8 for the XCD swizzle)
  gemm8<0, 0><<<128, 256, 0, stream>>>(win8, p8, proj_b, pbuf8, nullptr, nullptr, nullptr, 8, DSZ, 512);
  gemm8<1, 0><<<512, 256, 0, stream>>>(pbuf8, w18, dec_b1, abuf8, nullptr, nullptr, nullptr, 32, HSZ, DSZ);
  gemm8<0, 0><<<128, 256, 0, stream>>>(abuf8, w28, dec_b2, dbuf8, nullptr, nullptr, nullptr, 8, DSZ, HSZ);
  // lm head: 394 m-tiles x 16 n-tiles = 6304 blocks
  gemm8<0, 1><<<6304, 256, 0, stream>>>(lm8, dbuf8, nullptr, nullptr, outF, pm, ps, 16, NPOS, DSZ);

  // loss: merge partials + mean
  lsemerge_kernel<<<dim3(NPOS / 256), 256, 0, stream>>>(pm, ps, outF, labels, contrib);
  lossfinal_kernel<<<1, 256, 0, stream>>>(contrib, outF);
}

// Round 9
// 465.317 us; speedup vs baseline: 1.6395x; 1.1583x over previous
//
#include <hip/hip_runtime.h>

#define VSZ 50257
#define DSZ 1024
#define TSZ 512
#define BSZ 4
#define HSZ 4096
#define VPAD 50432   // 394*128
#define NCH (VPAD / 64)   // 788 v-stripes of 64
#define NPOS 2048
#define QS 16.0f
#define DQS (1.0f / 256.0f)
#define CG 32        // stage-1 chunk groups
#define CPC 25       // chunks per group (32*25 = 800 >= 788)

typedef __attribute__((ext_vector_type(4))) float f32x4;

#define GLD16(gp, lp) __builtin_amdgcn_global_load_lds( \
  (const __attribute__((address_space(1))) unsigned int*)(gp), \
  (__attribute__((address_space(3))) unsigned int*)(lp), 16, 0, 0)

__device__ __forceinline__ float gelu_f(float x) {
  float x3 = x * x * x;
  float u = 0.7978845608028654f * (x + 0.044715f * x3);
  return 0.5f * x * (1.f + tanhf(u));
}

__device__ __forceinline__ unsigned char q8(float v) {
  return (unsigned char)__builtin_amdgcn_cvt_pk_fp8_f32(v * QS, v * QS, 0, 0);
}

// -------- all weight transposes fused: f32 (R x C) -> fp8 x16 (Cpad x R), 64x64 tiles
__global__ __launch_bounds__(256) void transpose_all(
    const float* __restrict__ lm_w, const float* __restrict__ dw1,
    const float* __restrict__ dw2, const float* __restrict__ pw,
    unsigned char* __restrict__ lm8, unsigned char* __restrict__ w18,
    unsigned char* __restrict__ w28, unsigned char* __restrict__ p8) {
  __shared__ float tile[64][65];
  int bid = blockIdx.x;
  const float* src; unsigned char* dst; int R, C, Cpad, bx, by;
  if (bid < 12608)      { src = lm_w; dst = lm8; R = DSZ; C = VSZ; Cpad = VPAD; bx = bid % 788; by = bid / 788; }
  else if (bid < 13632) { int b = bid - 12608; src = dw1; dst = w18; R = DSZ; C = HSZ; Cpad = HSZ; bx = b % 64; by = b / 64; }
  else if (bid < 14656) { int b = bid - 13632; src = dw2; dst = w28; R = HSZ; C = DSZ; Cpad = DSZ; bx = b % 16; by = b / 16; }
  else                  { int b = bid - 14656; src = pw;  dst = p8;  R = 512; C = DSZ; Cpad = DSZ; bx = b % 16; by = b / 16; }
  int c0 = bx * 64, r0 = by * 64;
  int tid = threadIdx.x;
  int wv = tid >> 6, ln = tid & 63;
  int c = c0 + ln;
#pragma unroll 4
  for (int i = 0; i < 16; ++i) {
    int r = i * 4 + wv;
    tile[r][ln] = (c < C) ? src[(size_t)(r0 + r) * C + c] : 0.f;
  }
  __syncthreads();
  int ccb = tid >> 4;
  int r4 = (tid & 15) * 4;
#pragma unroll
  for (int j = 0; j < 4; ++j) {
    int cc = ccb + j * 16;
    if (c0 + cc >= Cpad) continue;
    unsigned int u = __builtin_amdgcn_cvt_pk_fp8_f32(QS * tile[r4 + 0][cc], QS * tile[r4 + 1][cc], 0, 0);
    u = __builtin_amdgcn_cvt_pk_fp8_f32(QS * tile[r4 + 2][cc], QS * tile[r4 + 3][cc], u, 1);
    *(unsigned int*)(dst + (size_t)(c0 + cc) * R + r0 + r4) = u;
  }
}

// -------- encoder layer 1 partials: K-split dot over d-chunk of 128
#define KS1 8
__global__ __launch_bounds__(256) void enc1p_kernel(const int* __restrict__ ids,
                                                    const float* __restrict__ wte,
                                                    const float* __restrict__ w1,
                                                    float* __restrict__ t1p) {
  int b = blockIdx.x;
  int h = blockIdx.y * 256 + threadIdx.x;
  int kc = blockIdx.z;
  int tok = ids[b * TSZ + (TSZ - 1)];
  const float* ev = wte + (size_t)tok * DSZ + kc * (DSZ / KS1);
  const float* w = w1 + (size_t)kc * (DSZ / KS1) * HSZ + h;
  float s = 0.f;
#pragma unroll 4
  for (int d = 0; d < DSZ / KS1; ++d) s += ev[d] * w[(size_t)d * HSZ];
  t1p[((size_t)(b * KS1 + kc)) * HSZ + h] = s;
}

// -------- encoder layer 2 partials (enc1 combine + gelu fused in):
#define KS2 16
__global__ __launch_bounds__(256) void enc2p_kernel(const float* __restrict__ t1p,
                                                    const float* __restrict__ b1,
                                                    const float* __restrict__ w2,
                                                    float* __restrict__ ep) {
  __shared__ float ts[256];
  int b = blockIdx.x;
  int i = blockIdx.y * 256 + threadIdx.x;
  int kc = blockIdx.z;
  int h = kc * 256 + threadIdx.x;
  float s0 = b1[h];
#pragma unroll
  for (int cc = 0; cc < KS1; ++cc) s0 += t1p[((size_t)(b * KS1 + cc)) * HSZ + h];
  ts[threadIdx.x] = gelu_f(s0);
  __syncthreads();
  const float* w = w2 + (size_t)kc * 256 * DSZ + i;
  float s = 0.f;
#pragma unroll 4
  for (int j = 0; j < 256; ++j) s += ts[j] * w[(size_t)j * DSZ];
  ep[((size_t)(b * KS2 + kc)) * DSZ + i] = s;
}

__global__ __launch_bounds__(256) void enc2c_kernel(const float* __restrict__ ep,
                                                    const float* __restrict__ b2,
                                                    float* __restrict__ e) {
  int idx = blockIdx.x * 256 + threadIdx.x;
  int b = idx >> 10, i = idx & (DSZ - 1);
  float s = b2[i];
#pragma unroll
  for (int kc = 0; kc < KS2; ++kc) s += ep[((size_t)(b * KS2 + kc)) * DSZ + i];
  e[idx] = s;
}

// -------- windows: win8[b*T+t][j] = fp8(e[b][t+j] * 16)
__global__ void win8_kernel(const float* __restrict__ e, unsigned char* __restrict__ win8) {
  int blk = blockIdx.x;
  int b = blk >> 9, t = blk & 511;
  const float* eb = e + b * DSZ;
  for (int j = threadIdx.x; j < 512; j += 256)
    win8[(size_t)blk * 512 + j] = q8(eb[t + j]);
}

// -------- unified fp8 GEMM: C[m][n] = (1/256) sum_k A8[m][k]*B8[n][k]
// 128x128 tile, BK=64 (64B rows), 3-buffer LDS ring (48 KB, 3 blocks/CU),
// prefetch depth 2 with counted vmcnt(8) (covers L2/most HBM latency),
// 16B-pair rotation layout (2-way banks = free).
// MODE 0: +bias, opt gelu, out fp8 x16 row-major [M][N].
// MODE 1: lm head: fused softmax partials + LDS-restaged f32 stores.
template<int GELU, int MODE>
__global__ __launch_bounds__(256, 3) void gemm8(
    const unsigned char* __restrict__ A, const unsigned char* __restrict__ Bm,
    const float* __restrict__ bias, unsigned char* __restrict__ out8,
    float* __restrict__ outF, float* __restrict__ pm, float* __restrict__ ps,
    int NT, int N, int K) {
  __shared__ __align__(16) char SM[49152];   // 3 x 16 KB ring; MODE1 epi reuse
  const int tid = threadIdx.x;
  const int lane = tid & 63;
  const int wave = tid >> 6;
  const int wr = (wave >> 1) * 64, wc = (wave & 1) * 64;
  const int l15 = lane & 15, l4 = lane >> 4;

  const int cpx = (int)gridDim.x >> 3;
  const int wg = ((int)blockIdx.x & 7) * cpx + ((int)blockIdx.x >> 3);
  const int m0 = (wg / NT) * 128, n0 = (wg % NT) * 128;

  f32x4 acc[4][4];
#pragma unroll
  for (int i = 0; i < 4; ++i)
#pragma unroll
    for (int j = 0; j < 4; ++j) acc[i][j] = (f32x4){0.f, 0.f, 0.f, 0.f};

  // staging: rows of 64 B (64 k), phys 16B-pair = (pair + (row>>1)) & 3
  const int ppair = lane & 3;
  const int row0 = wave * 16 + (lane >> 2);
  const int row1 = row0 + 64;
  const int og0 = (ppair - (row0 >> 1)) & 3;
  const int og1 = (ppair - (row1 >> 1)) & 3;
  const unsigned char* a0 = A + (size_t)(m0 + row0) * K + og0 * 16;
  const unsigned char* a1 = A + (size_t)(m0 + row1) * K + og1 * 16;
  const unsigned char* b0 = Bm + (size_t)(n0 + row0) * K + og0 * 16;
  const unsigned char* b1 = Bm + (size_t)(n0 + row1) * K + og1 * 16;

#define STG8(tt, bufb) do { \
    GLD16(a0 + (size_t)(tt) * 64, SM + (bufb) + wave * 1024); \
    GLD16(a1 + (size_t)(tt) * 64, SM + (bufb) + 4096 + wave * 1024); \
    GLD16(b0 + (size_t)(tt) * 64, SM + (bufb) + 8192 + wave * 1024); \
    GLD16(b1 + (size_t)(tt) * 64, SM + (bufb) + 12288 + wave * 1024); \
  } while (0)

  const int KT = K >> 6;
  STG8(0, 0);
  if (KT > 1) STG8(1, 16384);
  int cb = 0;
  for (int t = 0; t < KT; ++t) {
    if (t + 2 < KT) {
      int nb = cb + 32768; if (nb >= 49152) nb -= 49152;   // buffer (t+2)%3
      STG8(t + 2, nb);
      asm volatile("s_waitcnt vmcnt(8)" ::: "memory");   // tile t landed; t+1,t+2 in flight
    } else if (t + 1 < KT) {
      asm volatile("s_waitcnt vmcnt(4)" ::: "memory");
    } else {
      asm volatile("s_waitcnt vmcnt(0)" ::: "memory");
    }
    __builtin_amdgcn_s_barrier();
    asm volatile("" ::: "memory");
    long af[4][2], bfr[4][2];
#pragma unroll
    for (int mi = 0; mi < 4; ++mi) {
      const int row = wr + mi * 16 + l15;
#pragma unroll
      for (int kk = 0; kk < 2; ++kk) {
        const int ph = ((kk * 2 + (l4 >> 1)) + (row >> 1)) & 3;
        af[mi][kk] = *(const long*)(SM + cb + row * 64 + ph * 16 + (l4 & 1) * 8);
      }
    }
#pragma unroll
    for (int ni = 0; ni < 4; ++ni) {
      const int row = wc + ni * 16 + l15;
#pragma unroll
      for (int kk = 0; kk < 2; ++kk) {
        const int ph = ((kk * 2 + (l4 >> 1)) + (row >> 1)) & 3;
        bfr[ni][kk] = *(const long*)(SM + cb + 8192 + row * 64 + ph * 16 + (l4 & 1) * 8);
      }
    }
    asm volatile("s_waitcnt lgkmcnt(0)" ::: "memory");
    __builtin_amdgcn_sched_barrier(0);
    __builtin_amdgcn_s_setprio(1);
#pragma unroll
    for (int kk = 0; kk < 2; ++kk)
#pragma unroll
      for (int mi = 0; mi < 4; ++mi)
#pragma unroll
        for (int ni = 0; ni < 4; ++ni)
          acc[mi][ni] = __builtin_amdgcn_mfma_f32_16x16x32_fp8_fp8(
              af[mi][kk], bfr[ni][kk], acc[mi][ni], 0, 0, 0);
    __builtin_amdgcn_s_setprio(0);
    __builtin_amdgcn_s_barrier();
    asm volatile("" ::: "memory");
    cb += 16384; if (cb >= 49152) cb = 0;
  }
#undef STG8

  if (MODE == 0) {
#pragma unroll
    for (int ni = 0; ni < 4; ++ni) {
      int n = n0 + wc + ni * 16 + l15;
      float bv = bias[n];
#pragma unroll
      for (int mi = 0; mi < 4; ++mi) {
#pragma unroll
        for (int r = 0; r < 4; ++r) {
          int m = m0 + wr + mi * 16 + l4 * 4 + r;
          float v = acc[mi][ni][r] * DQS + bv;
          if (GELU) v = gelu_f(v);
          out8[(size_t)m * N + n] = q8(v);
        }
      }
    }
  } else {
    // dequantize accumulators to true logits
#pragma unroll
    for (int i = 0; i < 4; ++i)
#pragma unroll
      for (int j = 0; j < 4; ++j)
#pragma unroll
        for (int r = 0; r < 4; ++r) acc[i][j][r] *= DQS;

    // ---- fused softmax partials per 64-v stripe
    const int ch = (m0 + wr) >> 6;
#pragma unroll
    for (int ni = 0; ni < 4; ++ni) {
      int n = n0 + wc + ni * 16 + l15;   // pos = b*T + t
      float mloc = -1e30f, sloc = 0.f;
#pragma unroll
      for (int mi = 0; mi < 4; ++mi) {
        int vbase = m0 + wr + mi * 16 + l4 * 4;
#pragma unroll
        for (int r = 0; r < 4; ++r)
          if (vbase + r < VSZ) mloc = fmaxf(mloc, acc[mi][ni][r]);
      }
#pragma unroll
      for (int mi = 0; mi < 4; ++mi) {
        int vbase = m0 + wr + mi * 16 + l4 * 4;
#pragma unroll
        for (int r = 0; r < 4; ++r)
          if (vbase + r < VSZ) sloc += __expf(acc[mi][ni][r] - mloc);
      }
#pragma unroll
      for (int off = 16; off <= 32; off <<= 1) {
        float mo = __shfl_xor(mloc, off, 64);
        float so = __shfl_xor(sloc, off, 64);
        float nm = fmaxf(mloc, mo);
        sloc = sloc * __expf(mloc - nm) + so * __expf(mo - nm);
        mloc = nm;
      }
      if (l4 == 0) {
        pm[(size_t)ch * NPOS + n] = mloc;
        ps[(size_t)ch * NPOS + n] = sloc;
      }
    }

    // ---- LDS-restaged aligned f32 stores: 4 quarters of 32 v-rows x 128 t
    float* epi = (float*)SM;                 // [32][132] = 16.9 KB
    const int bb = n0 >> 9, t0 = n0 & 511;
    float* outG = outF + 1 + (size_t)bb * VSZ * TSZ + t0;
    const int trow = tid >> 5;
    const int lofs = (tid & 31) * 4;
#pragma unroll
    for (int q = 0; q < 4; ++q) {
      __builtin_amdgcn_s_barrier();
      asm volatile("" ::: "memory");
      if ((wave >> 1) == (q >> 1)) {
        const int miBase = (q & 1) * 2;
#pragma unroll
        for (int mi2 = 0; mi2 < 2; ++mi2)
#pragma unroll
          for (int ni = 0; ni < 4; ++ni)
#pragma unroll
            for (int r = 0; r < 4; ++r)
              epi[(mi2 * 16 + l4 * 4 + r) * 132 + wc + ni * 16 + l15] =
                  acc[miBase + mi2][ni][r];
      }
      __builtin_amdgcn_s_barrier();
      asm volatile("" ::: "memory");
#pragma unroll
      for (int p = 0; p < 4; ++p) {
        int row = p * 8 + trow;
        int v = m0 + q * 32 + row;
        if (v < VSZ) {
          f32x4 val = *(const f32x4*)&epi[row * 132 + lofs];
          float* gp = outG + (size_t)v * TSZ + lofs;
          gp[0] = val[0]; gp[1] = val[1]; gp[2] = val[2]; gp[3] = val[3];
        }
      }
    }
  }
}

// -------- loss stage 1: merge 25-chunk groups (256 blocks = full GPU)
__global__ __launch_bounds__(256) void lsestage1_kernel(const float* __restrict__ pm,
                                                        const float* __restrict__ ps,
                                                        float* __restrict__ pm2,
                                                        float* __restrict__ ps2) {
  int pos = (blockIdx.x & 7) * 256 + threadIdx.x;
  int cg = blockIdx.x >> 3;
  int c0 = cg * CPC;
  int c1 = c0 + CPC; if (c1 > NCH) c1 = NCH;
  float m = -1e30f, s = 0.f;
  for (int c = c0; c < c1; ++c) {
    float cm = pm[(size_t)c * NPOS + pos];
    float cs = ps[(size_t)c * NPOS + pos];
    float nm = fmaxf(m, cm);
    s = s * __expf(m - nm) + cs * __expf(cm - nm);
    m = nm;
  }
  pm2[(size_t)cg * NPOS + pos] = m;
  ps2[(size_t)cg * NPOS + pos] = s;
}

// -------- loss stage 2: merge 32 groups per position, gather label logit
__global__ __launch_bounds__(256) void lsemerge_kernel(const float* __restrict__ pm2,
                                                       const float* __restrict__ ps2,
                                                       const float* __restrict__ outF,
                                                       const int* __restrict__ labels,
                                                       float* __restrict__ contrib) {
  int pos = blockIdx.x * 256 + threadIdx.x;
  float m[4] = {-1e30f, -1e30f, -1e30f, -1e30f};
  float s[4] = {0.f, 0.f, 0.f, 0.f};
  for (int c = 0; c < CG; c += 4) {
#pragma unroll
    for (int j = 0; j < 4; ++j) {
      float cm = pm2[(size_t)(c + j) * NPOS + pos];
      float cs = ps2[(size_t)(c + j) * NPOS + pos];
      float nm = fmaxf(m[j], cm);
      s[j] = s[j] * __expf(m[j] - nm) + cs * __expf(cm - nm);
      m[j] = nm;
    }
  }
#pragma unroll
  for (int j = 1; j < 4; ++j) {
    float nm = fmaxf(m[0], m[j]);
    s[0] = s[0] * __expf(m[0] - nm) + s[j] * __expf(m[j] - nm);
    m[0] = nm;
  }
  float lse = m[0] + logf(s[0]);
  int b = pos >> 9, t = pos & 511;
  int lab = labels[pos];
  float x = outF[1 + (size_t)b * VSZ * TSZ + (size_t)lab * TSZ + t];
  contrib[pos] = lse - x;
}

__global__ __launch_bounds__(256) void lossfinal_kernel(const float* __restrict__ contrib,
                                                        float* __restrict__ dout) {
  __shared__ float red[256];
  int tid = threadIdx.x;
  float a = 0.f;
  for (int i = tid; i < NPOS; i += 256) a += contrib[i];
  red[tid] = a;
  __syncthreads();
  for (int off = 128; off; off >>= 1) {
    if (tid < off) red[tid] += red[tid + off];
    __syncthreads();
  }
  if (tid == 0) dout[0] = red[0] / (float)NPOS;
}

extern "C" void kernel_launch(void* const* d_in, const int* in_sizes, int n_in,
                              void* d_out, int out_size, void* d_ws, size_t ws_size,
                              hipStream_t stream) {
  const int* input_ids = (const int*)d_in[0];
  const int* labels    = (const int*)d_in[1];
  const float* wte     = (const float*)d_in[2];
  const float* enc_w1  = (const float*)d_in[3];
  const float* enc_b1  = (const float*)d_in[4];
  const float* enc_w2  = (const float*)d_in[5];
  const float* enc_b2  = (const float*)d_in[6];
  const float* proj_w  = (const float*)d_in[7];
  const float* proj_b  = (const float*)d_in[8];
  const float* dec_w1  = (const float*)d_in[9];
  const float* dec_b1  = (const float*)d_in[10];
  const float* dec_w2  = (const float*)d_in[11];
  const float* dec_b2  = (const float*)d_in[12];
  const float* lm_w    = (const float*)d_in[13];
  float* outF = (float*)d_out;

  char* w = (char*)d_ws;
  size_t off = 0;
  unsigned char* lm8  = (unsigned char*)(w + off); off += (size_t)VPAD * DSZ;   // 51.6 MB
  unsigned char* w18  = (unsigned char*)(w + off); off += (size_t)HSZ * DSZ;    // 4 MB
  unsigned char* w28  = (unsigned char*)(w + off); off += (size_t)DSZ * HSZ;    // 4 MB
  unsigned char* p8   = (unsigned char*)(w + off); off += (size_t)DSZ * 512;    // 0.5 MB
  unsigned char* win8 = (unsigned char*)(w + off); off += (size_t)NPOS * 512;   // 1 MB
  unsigned char* pbuf8= (unsigned char*)(w + off); off += (size_t)NPOS * DSZ;   // 2 MB
  unsigned char* abuf8= (unsigned char*)(w + off); off += (size_t)NPOS * HSZ;   // 8 MB
  unsigned char* dbuf8= (unsigned char*)(w + off); off += (size_t)NPOS * DSZ;   // 2 MB
  float* e      = (float*)(w + off);  off += (size_t)BSZ * DSZ * 4;
  float* t1p    = (float*)(w + off);  off += (size_t)BSZ * KS1 * HSZ * 4;
  float* ep     = (float*)(w + off);  off += (size_t)BSZ * KS2 * DSZ * 4;
  float* contrib= (float*)(w + off);  off += (size_t)NPOS * 4;
  float* pm     = (float*)(w + off);  off += (size_t)NCH * NPOS * 4;            // 6.5 MB
  float* ps     = (float*)(w + off);  off += (size_t)NCH * NPOS * 4;            // 6.5 MB
  float* pm2    = (float*)(w + off);  off += (size_t)CG * NPOS * 4;             // 256 KB
  float* ps2    = (float*)(w + off);  off += (size_t)CG * NPOS * 4;             // 256 KB
  (void)ws_size; (void)in_sizes; (void)n_in; (void)out_size;

  // all weight transposes in one dispatch (all -> fp8 x16)
  transpose_all<<<14784, 256, 0, stream>>>(lm_w, dec_w1, dec_w2, proj_w, lm8, w18, w28, p8);

  // encoder on last token only (K-split for parallelism)
  enc1p_kernel<<<dim3(BSZ, HSZ / 256, KS1), 256, 0, stream>>>(input_ids, wte, enc_w1, t1p);
  enc2p_kernel<<<dim3(BSZ, DSZ / 256, KS2), 256, 0, stream>>>(t1p, enc_b1, enc_w2, ep);
  enc2c_kernel<<<dim3(BSZ * DSZ / 256), 256, 0, stream>>>(ep, enc_b2, e);
  win8_kernel<<<2048, 256, 0, stream>>>(e, win8);

  // fp8 GEMM chain (1D grids, all divisible by 8 for the XCD swizzle)
  gemm8<0, 0><<<128, 256, 0, stream>>>(win8, p8, proj_b, pbuf8, nullptr, nullptr, nullptr, 8, DSZ, 512);
  gemm8<1, 0><<<512, 256, 0, stream>>>(pbuf8, w18, dec_b1, abuf8, nullptr, nullptr, nullptr, 32, HSZ, DSZ);
  gemm8<0, 0><<<128, 256, 0, stream>>>(abuf8, w28, dec_b2, dbuf8, nullptr, nullptr, nullptr, 8, DSZ, HSZ);
  // lm head: 394 m-tiles x 16 n-tiles = 6304 blocks
  gemm8<0, 1><<<6304, 256, 0, stream>>>(lm8, dbuf8, nullptr, nullptr, outF, pm, ps, 16, NPOS, DSZ);

  // loss: two-stage merge + mean
  lsestage1_kernel<<<256, 256, 0, stream>>>(pm, ps, pm2, ps2);
  lsemerge_kernel<<<dim3(NPOS / 256), 256, 0, stream>>>(pm2, ps2, outF, labels, contrib);
  lossfinal_kernel<<<1, 256, 0, stream>>>(contrib, outF);
}

// Round 10
// 458.514 us; speedup vs baseline: 1.6638x; 1.0148x over previous
//
#include <hip/hip_runtime.h>

#define VSZ 50257
#define DSZ 1024
#define TSZ 512
#define BSZ 4
#define HSZ 4096
#define VPAD 50432   // 394*128
#define NCH (VPAD / 64)   // 788 v-stripes of 64
#define NPOS 2048
#define QS 16.0f
#define DQS (1.0f / 256.0f)
#define CG 32        // stage-1 chunk groups
#define CPC 25       // chunks per group (32*25 = 800 >= 788)

typedef __attribute__((ext_vector_type(4))) float f32x4;
typedef __attribute__((ext_vector_type(16))) float f32x16;
typedef __attribute__((ext_vector_type(4))) int i32x4;
typedef __attribute__((ext_vector_type(8))) int i32x8;

#define GLD16(gp, lp) __builtin_amdgcn_global_load_lds( \
  (const __attribute__((address_space(1))) unsigned int*)(gp), \
  (__attribute__((address_space(3))) unsigned int*)(lp), 16, 0, 0)

__device__ __forceinline__ float gelu_f(float x) {
  float x3 = x * x * x;
  float u = 0.7978845608028654f * (x + 0.044715f * x3);
  return 0.5f * x * (1.f + tanhf(u));
}

__device__ __forceinline__ unsigned char q8(float v) {
  return (unsigned char)__builtin_amdgcn_cvt_pk_fp8_f32(v * QS, v * QS, 0, 0);
}

// -------- all weight transposes fused: f32 (R x C) -> fp8 x16 (Cpad x R), 64x64 tiles
__global__ __launch_bounds__(256) void transpose_all(
    const float* __restrict__ lm_w, const float* __restrict__ dw1,
    const float* __restrict__ dw2, const float* __restrict__ pw,
    unsigned char* __restrict__ lm8, unsigned char* __restrict__ w18,
    unsigned char* __restrict__ w28, unsigned char* __restrict__ p8) {
  __shared__ float tile[64][65];
  int bid = blockIdx.x;
  const float* src; unsigned char* dst; int R, C, Cpad, bx, by;
  if (bid < 12608)      { src = lm_w; dst = lm8; R = DSZ; C = VSZ; Cpad = VPAD; bx = bid % 788; by = bid / 788; }
  else if (bid < 13632) { int b = bid - 12608; src = dw1; dst = w18; R = DSZ; C = HSZ; Cpad = HSZ; bx = b % 64; by = b / 64; }
  else if (bid < 14656) { int b = bid - 13632; src = dw2; dst = w28; R = HSZ; C = DSZ; Cpad = DSZ; bx = b % 16; by = b / 16; }
  else                  { int b = bid - 14656; src = pw;  dst = p8;  R = 512; C = DSZ; Cpad = DSZ; bx = b % 16; by = b / 16; }
  int c0 = bx * 64, r0 = by * 64;
  int tid = threadIdx.x;
  int wv = tid >> 6, ln = tid & 63;
  int c = c0 + ln;
#pragma unroll 4
  for (int i = 0; i < 16; ++i) {
    int r = i * 4 + wv;
    tile[r][ln] = (c < C) ? src[(size_t)(r0 + r) * C + c] : 0.f;
  }
  __syncthreads();
  int ccb = tid >> 4;
  int r4 = (tid & 15) * 4;
#pragma unroll
  for (int j = 0; j < 4; ++j) {
    int cc = ccb + j * 16;
    if (c0 + cc >= Cpad) continue;
    unsigned int u = __builtin_amdgcn_cvt_pk_fp8_f32(QS * tile[r4 + 0][cc], QS * tile[r4 + 1][cc], 0, 0);
    u = __builtin_amdgcn_cvt_pk_fp8_f32(QS * tile[r4 + 2][cc], QS * tile[r4 + 3][cc], u, 1);
    *(unsigned int*)(dst + (size_t)(c0 + cc) * R + r0 + r4) = u;
  }
}

// -------- encoder layer 1 partials: K-split dot over d-chunk of 128
#define KS1 8
__global__ __launch_bounds__(256) void enc1p_kernel(const int* __restrict__ ids,
                                                    const float* __restrict__ wte,
                                                    const float* __restrict__ w1,
                                                    float* __restrict__ t1p) {
  int b = blockIdx.x;
  int h = blockIdx.y * 256 + threadIdx.x;
  int kc = blockIdx.z;
  int tok = ids[b * TSZ + (TSZ - 1)];
  const float* ev = wte + (size_t)tok * DSZ + kc * (DSZ / KS1);
  const float* w = w1 + (size_t)kc * (DSZ / KS1) * HSZ + h;
  float s = 0.f;
#pragma unroll 4
  for (int d = 0; d < DSZ / KS1; ++d) s += ev[d] * w[(size_t)d * HSZ];
  t1p[((size_t)(b * KS1 + kc)) * HSZ + h] = s;
}

// -------- encoder layer 2 partials (enc1 combine + gelu fused in):
#define KS2 16
__global__ __launch_bounds__(256) void enc2p_kernel(const float* __restrict__ t1p,
                                                    const float* __restrict__ b1,
                                                    const float* __restrict__ w2,
                                                    float* __restrict__ ep) {
  __shared__ float ts[256];
  int b = blockIdx.x;
  int i = blockIdx.y * 256 + threadIdx.x;
  int kc = blockIdx.z;
  int h = kc * 256 + threadIdx.x;
  float s0 = b1[h];
#pragma unroll
  for (int cc = 0; cc < KS1; ++cc) s0 += t1p[((size_t)(b * KS1 + cc)) * HSZ + h];
  ts[threadIdx.x] = gelu_f(s0);
  __syncthreads();
  const float* w = w2 + (size_t)kc * 256 * DSZ + i;
  float s = 0.f;
#pragma unroll 4
  for (int j = 0; j < 256; ++j) s += ts[j] * w[(size_t)j * DSZ];
  ep[((size_t)(b * KS2 + kc)) * DSZ + i] = s;
}

__global__ __launch_bounds__(256) void enc2c_kernel(const float* __restrict__ ep,
                                                    const float* __restrict__ b2,
                                                    float* __restrict__ e) {
  int idx = blockIdx.x * 256 + threadIdx.x;
  int b = idx >> 10, i = idx & (DSZ - 1);
  float s = b2[i];
#pragma unroll
  for (int kc = 0; kc < KS2; ++kc) s += ep[((size_t)(b * KS2 + kc)) * DSZ + i];
  e[idx] = s;
}

// -------- windows: win8[b*T+t][j] = fp8(e[b][t+j] * 16)
__global__ void win8_kernel(const float* __restrict__ e, unsigned char* __restrict__ win8) {
  int blk = blockIdx.x;
  int b = blk >> 9, t = blk & 511;
  const float* eb = e + b * DSZ;
  for (int j = threadIdx.x; j < 512; j += 256)
    win8[(size_t)blk * 512 + j] = q8(eb[t + j]);
}

// -------- mid fp8 GEMM (proj/dec1/dec2): 16x16x32 fp8, 128x128 tile, BK=64,
// 3-buffer ring, depth-2 prefetch, 16B-pair rotation (unchanged, proven).
template<int GELU>
__global__ __launch_bounds__(256, 3) void gemm8(
    const unsigned char* __restrict__ A, const unsigned char* __restrict__ Bm,
    const float* __restrict__ bias, unsigned char* __restrict__ out8,
    int NT, int N, int K) {
  __shared__ __align__(16) char SM[49152];
  const int tid = threadIdx.x;
  const int lane = tid & 63;
  const int wave = tid >> 6;
  const int wr = (wave >> 1) * 64, wc = (wave & 1) * 64;
  const int l15 = lane & 15, l4 = lane >> 4;

  const int cpx = (int)gridDim.x >> 3;
  const int wg = ((int)blockIdx.x & 7) * cpx + ((int)blockIdx.x >> 3);
  const int m0 = (wg / NT) * 128, n0 = (wg % NT) * 128;

  f32x4 acc[4][4];
#pragma unroll
  for (int i = 0; i < 4; ++i)
#pragma unroll
    for (int j = 0; j < 4; ++j) acc[i][j] = (f32x4){0.f, 0.f, 0.f, 0.f};

  const int ppair = lane & 3;
  const int row0 = wave * 16 + (lane >> 2);
  const int row1 = row0 + 64;
  const int og0 = (ppair - (row0 >> 1)) & 3;
  const int og1 = (ppair - (row1 >> 1)) & 3;
  const unsigned char* a0 = A + (size_t)(m0 + row0) * K + og0 * 16;
  const unsigned char* a1 = A + (size_t)(m0 + row1) * K + og1 * 16;
  const unsigned char* b0 = Bm + (size_t)(n0 + row0) * K + og0 * 16;
  const unsigned char* b1 = Bm + (size_t)(n0 + row1) * K + og1 * 16;

#define STG8(tt, bufb) do { \
    GLD16(a0 + (size_t)(tt) * 64, SM + (bufb) + wave * 1024); \
    GLD16(a1 + (size_t)(tt) * 64, SM + (bufb) + 4096 + wave * 1024); \
    GLD16(b0 + (size_t)(tt) * 64, SM + (bufb) + 8192 + wave * 1024); \
    GLD16(b1 + (size_t)(tt) * 64, SM + (bufb) + 12288 + wave * 1024); \
  } while (0)

  const int KT = K >> 6;
  STG8(0, 0);
  if (KT > 1) STG8(1, 16384);
  int cb = 0;
  for (int t = 0; t < KT; ++t) {
    if (t + 2 < KT) {
      int nb = cb + 32768; if (nb >= 49152) nb -= 49152;
      STG8(t + 2, nb);
      asm volatile("s_waitcnt vmcnt(8)" ::: "memory");
    } else if (t + 1 < KT) {
      asm volatile("s_waitcnt vmcnt(4)" ::: "memory");
    } else {
      asm volatile("s_waitcnt vmcnt(0)" ::: "memory");
    }
    __builtin_amdgcn_s_barrier();
    asm volatile("" ::: "memory");
    long af[4][2], bfr[4][2];
#pragma unroll
    for (int mi = 0; mi < 4; ++mi) {
      const int row = wr + mi * 16 + l15;
#pragma unroll
      for (int kk = 0; kk < 2; ++kk) {
        const int ph = ((kk * 2 + (l4 >> 1)) + (row >> 1)) & 3;
        af[mi][kk] = *(const long*)(SM + cb + row * 64 + ph * 16 + (l4 & 1) * 8);
      }
    }
#pragma unroll
    for (int ni = 0; ni < 4; ++ni) {
      const int row = wc + ni * 16 + l15;
#pragma unroll
      for (int kk = 0; kk < 2; ++kk) {
        const int ph = ((kk * 2 + (l4 >> 1)) + (row >> 1)) & 3;
        bfr[ni][kk] = *(const long*)(SM + cb + 8192 + row * 64 + ph * 16 + (l4 & 1) * 8);
      }
    }
    asm volatile("s_waitcnt lgkmcnt(0)" ::: "memory");
    __builtin_amdgcn_sched_barrier(0);
    __builtin_amdgcn_s_setprio(1);
#pragma unroll
    for (int kk = 0; kk < 2; ++kk)
#pragma unroll
      for (int mi = 0; mi < 4; ++mi)
#pragma unroll
        for (int ni = 0; ni < 4; ++ni)
          acc[mi][ni] = __builtin_amdgcn_mfma_f32_16x16x32_fp8_fp8(
              af[mi][kk], bfr[ni][kk], acc[mi][ni], 0, 0, 0);
    __builtin_amdgcn_s_setprio(0);
    __builtin_amdgcn_s_barrier();
    asm volatile("" ::: "memory");
    cb += 16384; if (cb >= 49152) cb = 0;
  }
#undef STG8

#pragma unroll
  for (int ni = 0; ni < 4; ++ni) {
    int n = n0 + wc + ni * 16 + l15;
    float bv = bias[n];
#pragma unroll
    for (int mi = 0; mi < 4; ++mi) {
#pragma unroll
      for (int r = 0; r < 4; ++r) {
        int m = m0 + wr + mi * 16 + l4 * 4 + r;
        float v = acc[mi][ni][r] * DQS + bv;
        if (GELU) v = gelu_f(v);
        out8[(size_t)m * N + n] = q8(v);
      }
    }
  }
}

// -------- lm-head MX-fp8 GEMM: mfma_scale 32x32x64 (2x fp8 rate), 128x128 tile,
// BK=64, 3-buffer ring depth-2, slot-permuted LDS layout (conflict-free 32B reads),
// E8M0 scales = 123 (2^-4 each) fold in the 1/256 dequant.
// Slot perm: unit = 4 rows x 64B = 16 slots of 16B; slot(c,p) = 2c + (p>>1) + 8(p&1).
__global__ __launch_bounds__(256, 3) void gemmLM(
    const unsigned char* __restrict__ A, const unsigned char* __restrict__ Bm,
    float* __restrict__ outF, float* __restrict__ pm, float* __restrict__ ps) {
  __shared__ __align__(16) char SM[49152];
  const int tid = threadIdx.x;
  const int lane = tid & 63;
  const int wave = tid >> 6;
  const int wr = (wave >> 1) * 64, wc = (wave & 1) * 64;
  const int l31 = lane & 31, hi = lane >> 5;

  const int cpx = (int)gridDim.x >> 3;
  const int wg = ((int)blockIdx.x & 7) * cpx + ((int)blockIdx.x >> 3);
  const int m0 = (wg >> 4) * 128, n0 = (wg & 15) * 128;

  f32x16 acc[2][2];
#pragma unroll
  for (int i = 0; i < 2; ++i)
#pragma unroll
    for (int j = 0; j < 2; ++j)
#pragma unroll
      for (int r = 0; r < 16; ++r) acc[i][j][r] = 0.f;

  // staging source permutation: lane L -> window row 4*(L>>4) + ((L>>1)&3),
  // k-byte 16*(2*(L&1) + ((L>>3)&1)); GLD16 dest linear (lane*16).
  const int urow = (lane >> 4) * 4 + ((lane >> 1) & 3);
  const int kb = ((lane & 1) * 2 + ((lane >> 3) & 1)) * 16;
  const int row0 = wave * 16 + urow;
  const int row1 = row0 + 64;
  const unsigned char* a0 = A + (size_t)(m0 + row0) * DSZ + kb;
  const unsigned char* a1 = A + (size_t)(m0 + row1) * DSZ + kb;
  const unsigned char* b0 = Bm + (size_t)(n0 + row0) * DSZ + kb;
  const unsigned char* b1 = Bm + (size_t)(n0 + row1) * DSZ + kb;

#define STGL(tt, bufb) do { \
    GLD16(a0 + (size_t)(tt) * 64, SM + (bufb) + wave * 1024); \
    GLD16(a1 + (size_t)(tt) * 64, SM + (bufb) + 4096 + wave * 1024); \
    GLD16(b0 + (size_t)(tt) * 64, SM + (bufb) + 8192 + wave * 1024); \
    GLD16(b1 + (size_t)(tt) * 64, SM + (bufb) + 12288 + wave * 1024); \
  } while (0)

  STGL(0, 0);
  STGL(1, 16384);
  int cb = 0;
  for (int t = 0; t < 16; ++t) {
    if (t + 2 < 16) {
      int nb = cb + 32768; if (nb >= 49152) nb -= 49152;
      STGL(t + 2, nb);
      asm volatile("s_waitcnt vmcnt(8)" ::: "memory");
    } else if (t + 1 < 16) {
      asm volatile("s_waitcnt vmcnt(4)" ::: "memory");
    } else {
      asm volatile("s_waitcnt vmcnt(0)" ::: "memory");
    }
    __builtin_amdgcn_s_barrier();
    asm volatile("" ::: "memory");
    // fragment reads: per frag 2 x b128; unit = (F + l31)>>2, slot = 2c + hi + 8j
    i32x8 a8[2], b8[2];
#pragma unroll
    for (int mf = 0; mf < 2; ++mf) {
      const int ub = ((wr + mf * 32) >> 2) + (l31 >> 2);
      const int s0 = 2 * (l31 & 3) + hi;
      i32x4 q0 = *(const i32x4*)(SM + cb + ub * 256 + s0 * 16);
      i32x4 q1 = *(const i32x4*)(SM + cb + ub * 256 + (s0 + 8) * 16);
      a8[mf] = __builtin_shufflevector(q0, q1, 0, 1, 2, 3, 4, 5, 6, 7);
    }
#pragma unroll
    for (int nf = 0; nf < 2; ++nf) {
      const int ub = ((wc + nf * 32) >> 2) + (l31 >> 2);
      const int s0 = 2 * (l31 & 3) + hi;
      i32x4 q0 = *(const i32x4*)(SM + cb + 8192 + ub * 256 + s0 * 16);
      i32x4 q1 = *(const i32x4*)(SM + cb + 8192 + ub * 256 + (s0 + 8) * 16);
      b8[nf] = __builtin_shufflevector(q0, q1, 0, 1, 2, 3, 4, 5, 6, 7);
    }
    asm volatile("s_waitcnt lgkmcnt(0)" ::: "memory");
    __builtin_amdgcn_sched_barrier(0);
    __builtin_amdgcn_s_setprio(1);
#pragma unroll
    for (int mf = 0; mf < 2; ++mf)
#pragma unroll
      for (int nf = 0; nf < 2; ++nf)
        acc[mf][nf] = __builtin_amdgcn_mfma_scale_f32_32x32x64_f8f6f4(
            a8[mf], b8[nf], acc[mf][nf], 0, 0, 0, 123, 0, 123);
    __builtin_amdgcn_s_setprio(0);
    __builtin_amdgcn_s_barrier();
    asm volatile("" ::: "memory");
    cb += 16384; if (cb >= 49152) cb = 0;
  }
#undef STGL

  // ---- fused softmax partials: wave's 64 v-rows = stripe ch
  // C/D: col = l31, row = (reg&3) + 8*(reg>>2) + 4*hi
  const int ch = (m0 + wr) >> 6;
#pragma unroll
  for (int nf = 0; nf < 2; ++nf) {
    const int pos = n0 + wc + nf * 32 + l31;
    float mloc = -1e30f, sloc = 0.f;
#pragma unroll
    for (int mf = 0; mf < 2; ++mf) {
      const int vb = m0 + wr + mf * 32 + 4 * hi;
#pragma unroll
      for (int r = 0; r < 16; ++r) {
        const int v = vb + (r & 3) + 8 * (r >> 2);
        if (v < VSZ) mloc = fmaxf(mloc, acc[mf][nf][r]);
      }
    }
#pragma unroll
    for (int mf = 0; mf < 2; ++mf) {
      const int vb = m0 + wr + mf * 32 + 4 * hi;
#pragma unroll
      for (int r = 0; r < 16; ++r) {
        const int v = vb + (r & 3) + 8 * (r >> 2);
        if (v < VSZ) sloc += __expf(acc[mf][nf][r] - mloc);
      }
    }
    {
      float mo = __shfl_xor(mloc, 32, 64);
      float so = __shfl_xor(sloc, 32, 64);
      float nm = fmaxf(mloc, mo);
      sloc = sloc * __expf(mloc - nm) + so * __expf(mo - nm);
      mloc = nm;
    }
    if (hi == 0) {
      pm[(size_t)ch * NPOS + pos] = mloc;
      ps[(size_t)ch * NPOS + pos] = sloc;
    }
  }

  // ---- LDS-restaged aligned f32 stores: 4 quarters of 32 v-rows x 128 t
  float* epi = (float*)SM;                 // [32][132]
  const int bb = n0 >> 9, t0 = n0 & 511;
  float* outG = outF + 1 + (size_t)bb * VSZ * TSZ + t0;
  const int trow = tid >> 5;
  const int lofs = (tid & 31) * 4;
#pragma unroll
  for (int q = 0; q < 4; ++q) {
    __builtin_amdgcn_s_barrier();
    asm volatile("" ::: "memory");
    if ((wave >> 1) == (q >> 1)) {
      const int mf = q & 1;
#pragma unroll
      for (int nf = 0; nf < 2; ++nf)
#pragma unroll
        for (int r = 0; r < 16; ++r)
          epi[((r & 3) + 8 * (r >> 2) + 4 * hi) * 132 + wc + nf * 32 + l31] =
              acc[mf][nf][r];
    }
    __builtin_amdgcn_s_barrier();
    asm volatile("" ::: "memory");
#pragma unroll
    for (int p = 0; p < 4; ++p) {
      int row = p * 8 + trow;
      int v = m0 + q * 32 + row;
      if (v < VSZ) {
        f32x4 val = *(const f32x4*)&epi[row * 132 + lofs];
        float* gp = outG + (size_t)v * TSZ + lofs;
        gp[0] = val[0]; gp[1] = val[1]; gp[2] = val[2]; gp[3] = val[3];
      }
    }
  }
}

// -------- loss stage 1: merge 25-chunk groups (256 blocks = full GPU)
__global__ __launch_bounds__(256) void lsestage1_kernel(const float* __restrict__ pm,
                                                        const float* __restrict__ ps,
                                                        float* __restrict__ pm2,
                                                        float* __restrict__ ps2) {
  int pos = (blockIdx.x & 7) * 256 + threadIdx.x;
  int cg = blockIdx.x >> 3;
  int c0 = cg * CPC;
  int c1 = c0 + CPC; if (c1 > NCH) c1 = NCH;
  float m = -1e30f, s = 0.f;
  for (int c = c0; c < c1; ++c) {
    float cm = pm[(size_t)c * NPOS + pos];
    float cs = ps[(size_t)c * NPOS + pos];
    float nm = fmaxf(m, cm);
    s = s * __expf(m - nm) + cs * __expf(cm - nm);
    m = nm;
  }
  pm2[(size_t)cg * NPOS + pos] = m;
  ps2[(size_t)cg * NPOS + pos] = s;
}

// -------- loss stage 2: merge 32 groups per position, gather label logit
__global__ __launch_bounds__(256) void lsemerge_kernel(const float* __restrict__ pm2,
                                                       const float* __restrict__ ps2,
                                                       const float* __restrict__ outF,
                                                       const int* __restrict__ labels,
                                                       float* __restrict__ contrib) {
  int pos = blockIdx.x * 256 + threadIdx.x;
  float m[4] = {-1e30f, -1e30f, -1e30f, -1e30f};
  float s[4] = {0.f, 0.f, 0.f, 0.f};
  for (int c = 0; c < CG; c += 4) {
#pragma unroll
    for (int j = 0; j < 4; ++j) {
      float cm = pm2[(size_t)(c + j) * NPOS + pos];
      float cs = ps2[(size_t)(c + j) * NPOS + pos];
      float nm = fmaxf(m[j], cm);
      s[j] = s[j] * __expf(m[j] - nm) + cs * __expf(cm - nm);
      m[j] = nm;
    }
  }
#pragma unroll
  for (int j = 1; j < 4; ++j) {
    float nm = fmaxf(m[0], m[j]);
    s[0] = s[0] * __expf(m[0] - nm) + s[j] * __expf(m[j] - nm);
    m[0] = nm;
  }
  float lse = m[0] + logf(s[0]);
  int b = pos >> 9, t = pos & 511;
  int lab = labels[pos];
  float x = outF[1 + (size_t)b * VSZ * TSZ + (size_t)lab * TSZ + t];
  contrib[pos] = lse - x;
}

__global__ __launch_bounds__(256) void lossfinal_kernel(const float* __restrict__ contrib,
                                                        float* __restrict__ dout) {
  __shared__ float red[256];
  int tid = threadIdx.x;
  float a = 0.f;
  for (int i = tid; i < NPOS; i += 256) a += contrib[i];
  red[tid] = a;
  __syncthreads();
  for (int off = 128; off; off >>= 1) {
    if (tid < off) red[tid] += red[tid + off];
    __syncthreads();
  }
  if (tid == 0) dout[0] = red[0] / (float)NPOS;
}

extern "C" void kernel_launch(void* const* d_in, const int* in_sizes, int n_in,
                              void* d_out, int out_size, void* d_ws, size_t ws_size,
                              hipStream_t stream) {
  const int* input_ids = (const int*)d_in[0];
  const int* labels    = (const int*)d_in[1];
  const float* wte     = (const float*)d_in[2];
  const float* enc_w1  = (const float*)d_in[3];
  const float* enc_b1  = (const float*)d_in[4];
  const float* enc_w2  = (const float*)d_in[5];
  const float* enc_b2  = (const float*)d_in[6];
  const float* proj_w  = (const float*)d_in[7];
  const float* proj_b  = (const float*)d_in[8];
  const float* dec_w1  = (const float*)d_in[9];
  const float* dec_b1  = (const float*)d_in[10];
  const float* dec_w2  = (const float*)d_in[11];
  const float* dec_b2  = (const float*)d_in[12];
  const float* lm_w    = (const float*)d_in[13];
  float* outF = (float*)d_out;

  char* w = (char*)d_ws;
  size_t off = 0;
  unsigned char* lm8  = (unsigned char*)(w + off); off += (size_t)VPAD * DSZ;   // 51.6 MB
  unsigned char* w18  = (unsigned char*)(w + off); off += (size_t)HSZ * DSZ;    // 4 MB
  unsigned char* w28  = (unsigned char*)(w + off); off += (size_t)DSZ * HSZ;    // 4 MB
  unsigned char* p8   = (unsigned char*)(w + off); off += (size_t)DSZ * 512;    // 0.5 MB
  unsigned char* win8 = (unsigned char*)(w + off); off += (size_t)NPOS * 512;   // 1 MB
  unsigned char* pbuf8= (unsigned char*)(w + off); off += (size_t)NPOS * DSZ;   // 2 MB
  unsigned char* abuf8= (unsigned char*)(w + off); off += (size_t)NPOS * HSZ;   // 8 MB
  unsigned char* dbuf8= (unsigned char*)(w + off); off += (size_t)NPOS * DSZ;   // 2 MB
  float* e      = (float*)(w + off);  off += (size_t)BSZ * DSZ * 4;
  float* t1p    = (float*)(w + off);  off += (size_t)BSZ * KS1 * HSZ * 4;
  float* ep     = (float*)(w + off);  off += (size_t)BSZ * KS2 * DSZ * 4;
  float* contrib= (float*)(w + off);  off += (size_t)NPOS * 4;
  float* pm     = (float*)(w + off);  off += (size_t)NCH * NPOS * 4;            // 6.5 MB
  float* ps     = (float*)(w + off);  off += (size_t)NCH * NPOS * 4;            // 6.5 MB
  float* pm2    = (float*)(w + off);  off += (size_t)CG * NPOS * 4;             // 256 KB
  float* ps2    = (float*)(w + off);  off += (size_t)CG * NPOS * 4;             // 256 KB
  (void)ws_size; (void)in_sizes; (void)n_in; (void)out_size;

  // all weight transposes in one dispatch (all -> fp8 x16)
  transpose_all<<<14784, 256, 0, stream>>>(lm_w, dec_w1, dec_w2, proj_w, lm8, w18, w28, p8);

  // encoder on last token only (K-split for parallelism)
  enc1p_kernel<<<dim3(BSZ, HSZ / 256, KS1), 256, 0, stream>>>(input_ids, wte, enc_w1, t1p);
  enc2p_kernel<<<dim3(BSZ, DSZ / 256, KS2), 256, 0, stream>>>(t1p, enc_b1, enc_w2, ep);
  enc2c_kernel<<<dim3(BSZ * DSZ / 256), 256, 0, stream>>>(ep, enc_b2, e);
  win8_kernel<<<2048, 256, 0, stream>>>(e, win8);

  // fp8 GEMM chain (1D grids, all divisible by 8 for the XCD swizzle)
  gemm8<0><<<128, 256, 0, stream>>>(win8, p8, proj_b, pbuf8, 8, DSZ, 512);
  gemm8<1><<<512, 256, 0, stream>>>(pbuf8, w18, dec_b1, abuf8, 32, HSZ, DSZ);
  gemm8<0><<<128, 256, 0, stream>>>(abuf8, w28, dec_b2, dbuf8, 8, DSZ, HSZ);
  // lm head MX-fp8: 394 m-tiles x 16 n-tiles = 6304 blocks
  gemmLM<<<6304, 256, 0, stream>>>(lm8, dbuf8, outF, pm, ps);

  // loss: two-stage merge + mean
  lsestage1_kernel<<<256, 256, 0, stream>>>(pm, ps, pm2, ps2);
  lsemerge_kernel<<<dim3(NPOS / 256), 256, 0, stream>>>(pm2, ps2, outF, labels, contrib);
  lossfinal_kernel<<<1, 256, 0, stream>>>(contrib, outF);
}

// Round 11
// 395.323 us; speedup vs baseline: 1.9298x; 1.1598x over previous
//
#include <hip/hip_runtime.h>

#define VSZ 50257
#define DSZ 1024
#define TSZ 512
#define BSZ 4
#define HSZ 4096
#define VPAD 50432   // 394*128
#define NCH (VPAD / 64)   // 788 v-stripes of 64
#define NPOS 2048
#define QS 16.0f
#define DQS (1.0f / 256.0f)
#define CG 32        // stage-1 chunk groups
#define CPC 25       // chunks per group (32*25 = 800 >= 788)

typedef __attribute__((ext_vector_type(4))) float f32x4;
typedef __attribute__((ext_vector_type(16))) float f32x16;
typedef __attribute__((ext_vector_type(4))) int i32x4;
typedef __attribute__((ext_vector_type(8))) int i32x8;

#define GLD16(gp, lp) __builtin_amdgcn_global_load_lds( \
  (const __attribute__((address_space(1))) unsigned int*)(gp), \
  (__attribute__((address_space(3))) unsigned int*)(lp), 16, 0, 0)

__device__ __forceinline__ float gelu_f(float x) {
  float x3 = x * x * x;
  float u = 0.7978845608028654f * (x + 0.044715f * x3);
  return 0.5f * x * (1.f + tanhf(u));
}

__device__ __forceinline__ unsigned char q8(float v) {
  return (unsigned char)__builtin_amdgcn_cvt_pk_fp8_f32(v * QS, v * QS, 0, 0);
}

// -------- all weight transposes fused: f32 (R x C) -> fp8 x16 (Cpad x R), 64x64 tiles
__global__ __launch_bounds__(256) void transpose_all(
    const float* __restrict__ lm_w, const float* __restrict__ dw1,
    const float* __restrict__ dw2, const float* __restrict__ pw,
    unsigned char* __restrict__ lm8, unsigned char* __restrict__ w18,
    unsigned char* __restrict__ w28, unsigned char* __restrict__ p8) {
  __shared__ float tile[64][65];
  int bid = blockIdx.x;
  const float* src; unsigned char* dst; int R, C, Cpad, bx, by;
  if (bid < 12608)      { src = lm_w; dst = lm8; R = DSZ; C = VSZ; Cpad = VPAD; bx = bid % 788; by = bid / 788; }
  else if (bid < 13632) { int b = bid - 12608; src = dw1; dst = w18; R = DSZ; C = HSZ; Cpad = HSZ; bx = b % 64; by = b / 64; }
  else if (bid < 14656) { int b = bid - 13632; src = dw2; dst = w28; R = HSZ; C = DSZ; Cpad = DSZ; bx = b % 16; by = b / 16; }
  else                  { int b = bid - 14656; src = pw;  dst = p8;  R = 512; C = DSZ; Cpad = DSZ; bx = b % 16; by = b / 16; }
  int c0 = bx * 64, r0 = by * 64;
  int tid = threadIdx.x;
  int wv = tid >> 6, ln = tid & 63;
  int c = c0 + ln;
#pragma unroll 4
  for (int i = 0; i < 16; ++i) {
    int r = i * 4 + wv;
    tile[r][ln] = (c < C) ? src[(size_t)(r0 + r) * C + c] : 0.f;
  }
  __syncthreads();
  int ccb = tid >> 4;
  int r4 = (tid & 15) * 4;
#pragma unroll
  for (int j = 0; j < 4; ++j) {
    int cc = ccb + j * 16;
    if (c0 + cc >= Cpad) continue;
    unsigned int u = __builtin_amdgcn_cvt_pk_fp8_f32(QS * tile[r4 + 0][cc], QS * tile[r4 + 1][cc], 0, 0);
    u = __builtin_amdgcn_cvt_pk_fp8_f32(QS * tile[r4 + 2][cc], QS * tile[r4 + 3][cc], u, 1);
    *(unsigned int*)(dst + (size_t)(c0 + cc) * R + r0 + r4) = u;
  }
}

// -------- encoder layer 1 partials: all 4 batch rows per block (w1 read once)
#define KS1 8
__global__ __launch_bounds__(256) void enc1p_kernel(const int* __restrict__ ids,
                                                    const float* __restrict__ wte,
                                                    const float* __restrict__ w1,
                                                    float* __restrict__ t1p) {
  __shared__ float ev[4][128];
  int h = blockIdx.x * 256 + threadIdx.x;
  int kc = blockIdx.y;
  for (int i = threadIdx.x; i < 512; i += 256) {
    int b = i >> 7, d = i & 127;
    int tok = ids[b * TSZ + (TSZ - 1)];
    ev[b][d] = wte[(size_t)tok * DSZ + kc * 128 + d];
  }
  __syncthreads();
  const float* w = w1 + (size_t)(kc * 128) * HSZ + h;
  float s0 = 0.f, s1 = 0.f, s2 = 0.f, s3 = 0.f;
#pragma unroll 4
  for (int d = 0; d < 128; ++d) {
    float wv = w[(size_t)d * HSZ];
    s0 += ev[0][d] * wv; s1 += ev[1][d] * wv;
    s2 += ev[2][d] * wv; s3 += ev[3][d] * wv;
  }
  t1p[((size_t)(0 * KS1 + kc)) * HSZ + h] = s0;
  t1p[((size_t)(1 * KS1 + kc)) * HSZ + h] = s1;
  t1p[((size_t)(2 * KS1 + kc)) * HSZ + h] = s2;
  t1p[((size_t)(3 * KS1 + kc)) * HSZ + h] = s3;
}

// -------- encoder layer 2 partials: all 4 batch rows per block (w2 read once)
#define KS2 16
__global__ __launch_bounds__(256) void enc2p_kernel(const float* __restrict__ t1p,
                                                    const float* __restrict__ b1,
                                                    const float* __restrict__ w2,
                                                    float* __restrict__ ep) {
  __shared__ float ts[4][256];
  int i = blockIdx.x * 256 + threadIdx.x;
  int kc = blockIdx.y;
  int h = kc * 256 + threadIdx.x;
  float bv = b1[h];
#pragma unroll
  for (int b = 0; b < 4; ++b) {
    float s0 = bv;
#pragma unroll
    for (int cc = 0; cc < KS1; ++cc) s0 += t1p[((size_t)(b * KS1 + cc)) * HSZ + h];
    ts[b][threadIdx.x] = gelu_f(s0);
  }
  __syncthreads();
  const float* w = w2 + (size_t)(kc * 256) * DSZ + i;
  float a0 = 0.f, a1 = 0.f, a2 = 0.f, a3 = 0.f;
#pragma unroll 4
  for (int j = 0; j < 256; ++j) {
    float wv = w[(size_t)j * DSZ];
    a0 += ts[0][j] * wv; a1 += ts[1][j] * wv;
    a2 += ts[2][j] * wv; a3 += ts[3][j] * wv;
  }
  ep[((size_t)(0 * KS2 + kc)) * DSZ + i] = a0;
  ep[((size_t)(1 * KS2 + kc)) * DSZ + i] = a1;
  ep[((size_t)(2 * KS2 + kc)) * DSZ + i] = a2;
  ep[((size_t)(3 * KS2 + kc)) * DSZ + i] = a3;
}

__global__ __launch_bounds__(256) void enc2c_kernel(const float* __restrict__ ep,
                                                    const float* __restrict__ b2,
                                                    float* __restrict__ e) {
  int idx = blockIdx.x * 256 + threadIdx.x;
  int b = idx >> 10, i = idx & (DSZ - 1);
  float s = b2[i];
#pragma unroll
  for (int kc = 0; kc < KS2; ++kc) s += ep[((size_t)(b * KS2 + kc)) * DSZ + i];
  e[idx] = s;
}

// -------- windows: win8[b*T+t][j] = fp8(e[b][t+j] * 16)
__global__ void win8_kernel(const float* __restrict__ e, unsigned char* __restrict__ win8) {
  int blk = blockIdx.x;
  int b = blk >> 9, t = blk & 511;
  const float* eb = e + b * DSZ;
  for (int j = threadIdx.x; j < 512; j += 256)
    win8[(size_t)blk * 512 + j] = q8(eb[t + j]);
}

// -------- mid fp8 GEMM (proj/dec1/dec2): 16x16x32 fp8, 128x128 tile, BK=64,
// 3-buffer ring, depth-2 prefetch, 16B-pair rotation (unchanged, proven).
template<int GELU>
__global__ __launch_bounds__(256, 3) void gemm8(
    const unsigned char* __restrict__ A, const unsigned char* __restrict__ Bm,
    const float* __restrict__ bias, unsigned char* __restrict__ out8,
    int NT, int N, int K) {
  __shared__ __align__(16) char SM[49152];
  const int tid = threadIdx.x;
  const int lane = tid & 63;
  const int wave = tid >> 6;
  const int wr = (wave >> 1) * 64, wc = (wave & 1) * 64;
  const int l15 = lane & 15, l4 = lane >> 4;

  const int cpx = (int)gridDim.x >> 3;
  const int wg = ((int)blockIdx.x & 7) * cpx + ((int)blockIdx.x >> 3);
  const int m0 = (wg / NT) * 128, n0 = (wg % NT) * 128;

  f32x4 acc[4][4];
#pragma unroll
  for (int i = 0; i < 4; ++i)
#pragma unroll
    for (int j = 0; j < 4; ++j) acc[i][j] = (f32x4){0.f, 0.f, 0.f, 0.f};

  const int ppair = lane & 3;
  const int row0 = wave * 16 + (lane >> 2);
  const int row1 = row0 + 64;
  const int og0 = (ppair - (row0 >> 1)) & 3;
  const int og1 = (ppair - (row1 >> 1)) & 3;
  const unsigned char* a0 = A + (size_t)(m0 + row0) * K + og0 * 16;
  const unsigned char* a1 = A + (size_t)(m0 + row1) * K + og1 * 16;
  const unsigned char* b0 = Bm + (size_t)(n0 + row0) * K + og0 * 16;
  const unsigned char* b1 = Bm + (size_t)(n0 + row1) * K + og1 * 16;

#define STG8(tt, bufb) do { \
    GLD16(a0 + (size_t)(tt) * 64, SM + (bufb) + wave * 1024); \
    GLD16(a1 + (size_t)(tt) * 64, SM + (bufb) + 4096 + wave * 1024); \
    GLD16(b0 + (size_t)(tt) * 64, SM + (bufb) + 8192 + wave * 1024); \
    GLD16(b1 + (size_t)(tt) * 64, SM + (bufb) + 12288 + wave * 1024); \
  } while (0)

  const int KT = K >> 6;
  STG8(0, 0);
  if (KT > 1) STG8(1, 16384);
  int cb = 0;
  for (int t = 0; t < KT; ++t) {
    if (t + 2 < KT) {
      int nb = cb + 32768; if (nb >= 49152) nb -= 49152;
      STG8(t + 2, nb);
      asm volatile("s_waitcnt vmcnt(8)" ::: "memory");
    } else if (t + 1 < KT) {
      asm volatile("s_waitcnt vmcnt(4)" ::: "memory");
    } else {
      asm volatile("s_waitcnt vmcnt(0)" ::: "memory");
    }
    __builtin_amdgcn_s_barrier();
    asm volatile("" ::: "memory");
    long af[4][2], bfr[4][2];
#pragma unroll
    for (int mi = 0; mi < 4; ++mi) {
      const int row = wr + mi * 16 + l15;
#pragma unroll
      for (int kk = 0; kk < 2; ++kk) {
        const int ph = ((kk * 2 + (l4 >> 1)) + (row >> 1)) & 3;
        af[mi][kk] = *(const long*)(SM + cb + row * 64 + ph * 16 + (l4 & 1) * 8);
      }
    }
#pragma unroll
    for (int ni = 0; ni < 4; ++ni) {
      const int row = wc + ni * 16 + l15;
#pragma unroll
      for (int kk = 0; kk < 2; ++kk) {
        const int ph = ((kk * 2 + (l4 >> 1)) + (row >> 1)) & 3;
        bfr[ni][kk] = *(const long*)(SM + cb + 8192 + row * 64 + ph * 16 + (l4 & 1) * 8);
      }
    }
    asm volatile("s_waitcnt lgkmcnt(0)" ::: "memory");
    __builtin_amdgcn_sched_barrier(0);
    __builtin_amdgcn_s_setprio(1);
#pragma unroll
    for (int kk = 0; kk < 2; ++kk)
#pragma unroll
      for (int mi = 0; mi < 4; ++mi)
#pragma unroll
        for (int ni = 0; ni < 4; ++ni)
          acc[mi][ni] = __builtin_amdgcn_mfma_f32_16x16x32_fp8_fp8(
              af[mi][kk], bfr[ni][kk], acc[mi][ni], 0, 0, 0);
    __builtin_amdgcn_s_setprio(0);
    __builtin_amdgcn_s_barrier();
    asm volatile("" ::: "memory");
    cb += 16384; if (cb >= 49152) cb = 0;
  }
#undef STG8

#pragma unroll
  for (int ni = 0; ni < 4; ++ni) {
    int n = n0 + wc + ni * 16 + l15;
    float bv = bias[n];
#pragma unroll
    for (int mi = 0; mi < 4; ++mi) {
#pragma unroll
      for (int r = 0; r < 4; ++r) {
        int m = m0 + wr + mi * 16 + l4 * 4 + r;
        float v = acc[mi][ni][r] * DQS + bv;
        if (GELU) v = gelu_f(v);
        out8[(size_t)m * N + n] = q8(v);
      }
    }
  }
}

// -------- lm-head MX-fp8 GEMM: mfma_scale 32x32x64 (2x fp8 rate), 128x128 tile,
// BK=64, 3-buffer ring depth-2. LDS = proven rotation layout (rows of 64B,
// phys pair = (logical + (row>>1)) & 3 -> 0 bank conflicts measured r6/r7);
// fragments read as 2 x b128 at rotated pair positions. E8M0 scales = 123
// (2^-4 each) fold in the 1/256 dequant. Nontemporal logit stores.
__global__ __launch_bounds__(256, 3) void gemmLM(
    const unsigned char* __restrict__ A, const unsigned char* __restrict__ Bm,
    float* __restrict__ outF, float* __restrict__ pm, float* __restrict__ ps) {
  __shared__ __align__(16) char SM[49152];
  const int tid = threadIdx.x;
  const int lane = tid & 63;
  const int wave = tid >> 6;
  const int wr = (wave >> 1) * 64, wc = (wave & 1) * 64;
  const int l31 = lane & 31, hi = lane >> 5;

  const int cpx = (int)gridDim.x >> 3;
  const int wg = ((int)blockIdx.x & 7) * cpx + ((int)blockIdx.x >> 3);
  const int m0 = (wg >> 4) * 128, n0 = (wg & 15) * 128;

  f32x16 acc[2][2];
#pragma unroll
  for (int i = 0; i < 2; ++i)
#pragma unroll
    for (int j = 0; j < 2; ++j)
#pragma unroll
      for (int r = 0; r < 16; ++r) acc[i][j][r] = 0.f;

  // staging: identical to gemm8 rotation (linear LDS dest, rotated global src)
  const int ppair = lane & 3;
  const int row0 = wave * 16 + (lane >> 2);
  const int row1 = row0 + 64;
  const int og0 = (ppair - (row0 >> 1)) & 3;
  const int og1 = (ppair - (row1 >> 1)) & 3;
  const unsigned char* a0 = A + (size_t)(m0 + row0) * DSZ + og0 * 16;
  const unsigned char* a1 = A + (size_t)(m0 + row1) * DSZ + og1 * 16;
  const unsigned char* b0 = Bm + (size_t)(n0 + row0) * DSZ + og0 * 16;
  const unsigned char* b1 = Bm + (size_t)(n0 + row1) * DSZ + og1 * 16;

#define STGL(tt, bufb) do { \
    GLD16(a0 + (size_t)(tt) * 64, SM + (bufb) + wave * 1024); \
    GLD16(a1 + (size_t)(tt) * 64, SM + (bufb) + 4096 + wave * 1024); \
    GLD16(b0 + (size_t)(tt) * 64, SM + (bufb) + 8192 + wave * 1024); \
    GLD16(b1 + (size_t)(tt) * 64, SM + (bufb) + 12288 + wave * 1024); \
  } while (0)

  STGL(0, 0);
  STGL(1, 16384);
  int cb = 0;
  for (int t = 0; t < 16; ++t) {
    if (t + 2 < 16) {
      int nb = cb + 32768; if (nb >= 49152) nb -= 49152;
      STGL(t + 2, nb);
      asm volatile("s_waitcnt vmcnt(8)" ::: "memory");
    } else if (t + 1 < 16) {
      asm volatile("s_waitcnt vmcnt(4)" ::: "memory");
    } else {
      asm volatile("s_waitcnt vmcnt(0)" ::: "memory");
    }
    __builtin_amdgcn_s_barrier();
    asm volatile("" ::: "memory");
    // fragment = 32B of k per lane: pairs {2hi, 2hi+1} at rotated positions
    i32x8 a8[2], b8[2];
#pragma unroll
    for (int mf = 0; mf < 2; ++mf) {
      const int row = wr + mf * 32 + l31;
      const char* base = SM + cb + row * 64;
      const int ph0 = (2 * hi + (row >> 1)) & 3;
      const int ph1 = (2 * hi + 1 + (row >> 1)) & 3;
      i32x4 q01 = *(const i32x4*)(base + ph0 * 16);
      i32x4 q23 = *(const i32x4*)(base + ph1 * 16);
      a8[mf] = __builtin_shufflevector(q01, q23, 0, 1, 2, 3, 4, 5, 6, 7);
    }
#pragma unroll
    for (int nf = 0; nf < 2; ++nf) {
      const int row = wc + nf * 32 + l31;
      const char* base = SM + cb + 8192 + row * 64;
      const int ph0 = (2 * hi + (row >> 1)) & 3;
      const int ph1 = (2 * hi + 1 + (row >> 1)) & 3;
      i32x4 q01 = *(const i32x4*)(base + ph0 * 16);
      i32x4 q23 = *(const i32x4*)(base + ph1 * 16);
      b8[nf] = __builtin_shufflevector(q01, q23, 0, 1, 2, 3, 4, 5, 6, 7);
    }
    asm volatile("s_waitcnt lgkmcnt(0)" ::: "memory");
    __builtin_amdgcn_sched_barrier(0);
    __builtin_amdgcn_s_setprio(1);
#pragma unroll
    for (int mf = 0; mf < 2; ++mf)
#pragma unroll
      for (int nf = 0; nf < 2; ++nf)
        acc[mf][nf] = __builtin_amdgcn_mfma_scale_f32_32x32x64_f8f6f4(
            a8[mf], b8[nf], acc[mf][nf], 0, 0, 0, 123, 0, 123);
    __builtin_amdgcn_s_setprio(0);
    __builtin_amdgcn_s_barrier();
    asm volatile("" ::: "memory");
    cb += 16384; if (cb >= 49152) cb = 0;
  }
#undef STGL

  // ---- fused softmax partials: wave's 64 v-rows = stripe ch
  // C/D: col = l31, row = (reg&3) + 8*(reg>>2) + 4*hi
  const int ch = (m0 + wr) >> 6;
#pragma unroll
  for (int nf = 0; nf < 2; ++nf) {
    const int pos = n0 + wc + nf * 32 + l31;
    float mloc = -1e30f, sloc = 0.f;
#pragma unroll
    for (int mf = 0; mf < 2; ++mf) {
      const int vb = m0 + wr + mf * 32 + 4 * hi;
#pragma unroll
      for (int r = 0; r < 16; ++r) {
        const int v = vb + (r & 3) + 8 * (r >> 2);
        if (v < VSZ) mloc = fmaxf(mloc, acc[mf][nf][r]);
      }
    }
#pragma unroll
    for (int mf = 0; mf < 2; ++mf) {
      const int vb = m0 + wr + mf * 32 + 4 * hi;
#pragma unroll
      for (int r = 0; r < 16; ++r) {
        const int v = vb + (r & 3) + 8 * (r >> 2);
        if (v < VSZ) sloc += __expf(acc[mf][nf][r] - mloc);
      }
    }
    {
      float mo = __shfl_xor(mloc, 32, 64);
      float so = __shfl_xor(sloc, 32, 64);
      float nm = fmaxf(mloc, mo);
      sloc = sloc * __expf(mloc - nm) + so * __expf(mo - nm);
      mloc = nm;
    }
    if (hi == 0) {
      pm[(size_t)ch * NPOS + pos] = mloc;
      ps[(size_t)ch * NPOS + pos] = sloc;
    }
  }

  // ---- LDS-restaged aligned f32 stores (nontemporal): 4 quarters of 32 v-rows
  float* epi = (float*)SM;                 // [32][132]
  const int bb = n0 >> 9, t0 = n0 & 511;
  float* outG = outF + 1 + (size_t)bb * VSZ * TSZ + t0;
  const int trow = tid >> 5;
  const int lofs = (tid & 31) * 4;
#pragma unroll
  for (int q = 0; q < 4; ++q) {
    __builtin_amdgcn_s_barrier();
    asm volatile("" ::: "memory");
    if ((wave >> 1) == (q >> 1)) {
      const int mf = q & 1;
#pragma unroll
      for (int nf = 0; nf < 2; ++nf)
#pragma unroll
        for (int r = 0; r < 16; ++r)
          epi[((r & 3) + 8 * (r >> 2) + 4 * hi) * 132 + wc + nf * 32 + l31] =
              acc[mf][nf][r];
    }
    __builtin_amdgcn_s_barrier();
    asm volatile("" ::: "memory");
#pragma unroll
    for (int p = 0; p < 4; ++p) {
      int row = p * 8 + trow;
      int v = m0 + q * 32 + row;
      if (v < VSZ) {
        f32x4 val = *(const f32x4*)&epi[row * 132 + lofs];
        float* gp = outG + (size_t)v * TSZ + lofs;
        __builtin_nontemporal_store(val[0], gp + 0);
        __builtin_nontemporal_store(val[1], gp + 1);
        __builtin_nontemporal_store(val[2], gp + 2);
        __builtin_nontemporal_store(val[3], gp + 3);
      }
    }
  }
}

// -------- loss stage 1: merge 25-chunk groups (256 blocks = full GPU)
__global__ __launch_bounds__(256) void lsestage1_kernel(const float* __restrict__ pm,
                                                        const float* __restrict__ ps,
                                                        float* __restrict__ pm2,
                                                        float* __restrict__ ps2) {
  int pos = (blockIdx.x & 7) * 256 + threadIdx.x;
  int cg = blockIdx.x >> 3;
  int c0 = cg * CPC;
  int c1 = c0 + CPC; if (c1 > NCH) c1 = NCH;
  float m = -1e30f, s = 0.f;
  for (int c = c0; c < c1; ++c) {
    float cm = pm[(size_t)c * NPOS + pos];
    float cs = ps[(size_t)c * NPOS + pos];
    float nm = fmaxf(m, cm);
    s = s * __expf(m - nm) + cs * __expf(cm - nm);
    m = nm;
  }
  pm2[(size_t)cg * NPOS + pos] = m;
  ps2[(size_t)cg * NPOS + pos] = s;
}

// -------- loss stage 2: merge 32 groups per position, gather label logit
__global__ __launch_bounds__(256) void lsemerge_kernel(const float* __restrict__ pm2,
                                                       const float* __restrict__ ps2,
                                                       const float* __restrict__ outF,
                                                       const int* __restrict__ labels,
                                                       float* __restrict__ contrib) {
  int pos = blockIdx.x * 256 + threadIdx.x;
  float m[4] = {-1e30f, -1e30f, -1e30f, -1e30f};
  float s[4] = {0.f, 0.f, 0.f, 0.f};
  for (int c = 0; c < CG; c += 4) {
#pragma unroll
    for (int j = 0; j < 4; ++j) {
      float cm = pm2[(size_t)(c + j) * NPOS + pos];
      float cs = ps2[(size_t)(c + j) * NPOS + pos];
      float nm = fmaxf(m[j], cm);
      s[j] = s[j] * __expf(m[j] - nm) + cs * __expf(cm - nm);
      m[j] = nm;
    }
  }
#pragma unroll
  for (int j = 1; j < 4; ++j) {
    float nm = fmaxf(m[0], m[j]);
    s[0] = s[0] * __expf(m[0] - nm) + s[j] * __expf(m[j] - nm);
    m[0] = nm;
  }
  float lse = m[0] + logf(s[0]);
  int b = pos >> 9, t = pos & 511;
  int lab = labels[pos];
  float x = outF[1 + (size_t)b * VSZ * TSZ + (size_t)lab * TSZ + t];
  contrib[pos] = lse - x;
}

__global__ __launch_bounds__(256) void lossfinal_kernel(const float* __restrict__ contrib,
                                                        float* __restrict__ dout) {
  __shared__ float red[256];
  int tid = threadIdx.x;
  float a = 0.f;
  for (int i = tid; i < NPOS; i += 256) a += contrib[i];
  red[tid] = a;
  __syncthreads();
  for (int off = 128; off; off >>= 1) {
    if (tid < off) red[tid] += red[tid + off];
    __syncthreads();
  }
  if (tid == 0) dout[0] = red[0] / (float)NPOS;
}

extern "C" void kernel_launch(void* const* d_in, const int* in_sizes, int n_in,
                              void* d_out, int out_size, void* d_ws, size_t ws_size,
                              hipStream_t stream) {
  const int* input_ids = (const int*)d_in[0];
  const int* labels    = (const int*)d_in[1];
  const float* wte     = (const float*)d_in[2];
  const float* enc_w1  = (const float*)d_in[3];
  const float* enc_b1  = (const float*)d_in[4];
  const float* enc_w2  = (const float*)d_in[5];
  const float* enc_b2  = (const float*)d_in[6];
  const float* proj_w  = (const float*)d_in[7];
  const float* proj_b  = (const float*)d_in[8];
  const float* dec_w1  = (const float*)d_in[9];
  const float* dec_b1  = (const float*)d_in[10];
  const float* dec_w2  = (const float*)d_in[11];
  const float* dec_b2  = (const float*)d_in[12];
  const float* lm_w    = (const float*)d_in[13];
  float* outF = (float*)d_out;

  char* w = (char*)d_ws;
  size_t off = 0;
  unsigned char* lm8  = (unsigned char*)(w + off); off += (size_t)VPAD * DSZ;   // 51.6 MB
  unsigned char* w18  = (unsigned char*)(w + off); off += (size_t)HSZ * DSZ;    // 4 MB
  unsigned char* w28  = (unsigned char*)(w + off); off += (size_t)DSZ * HSZ;    // 4 MB
  unsigned char* p8   = (unsigned char*)(w + off); off += (size_t)DSZ * 512;    // 0.5 MB
  unsigned char* win8 = (unsigned char*)(w + off); off += (size_t)NPOS * 512;   // 1 MB
  unsigned char* pbuf8= (unsigned char*)(w + off); off += (size_t)NPOS * DSZ;   // 2 MB
  unsigned char* abuf8= (unsigned char*)(w + off); off += (size_t)NPOS * HSZ;   // 8 MB
  unsigned char* dbuf8= (unsigned char*)(w + off); off += (size_t)NPOS * DSZ;   // 2 MB
  float* e      = (float*)(w + off);  off += (size_t)BSZ * DSZ * 4;
  float* t1p    = (float*)(w + off);  off += (size_t)BSZ * KS1 * HSZ * 4;
  float* ep     = (float*)(w + off);  off += (size_t)BSZ * KS2 * DSZ * 4;
  float* contrib= (float*)(w + off);  off += (size_t)NPOS * 4;
  float* pm     = (float*)(w + off);  off += (size_t)NCH * NPOS * 4;            // 6.5 MB
  float* ps     = (float*)(w + off);  off += (size_t)NCH * NPOS * 4;            // 6.5 MB
  float* pm2    = (float*)(w + off);  off += (size_t)CG * NPOS * 4;             // 256 KB
  float* ps2    = (float*)(w + off);  off += (size_t)CG * NPOS * 4;             // 256 KB
  (void)ws_size; (void)in_sizes; (void)n_in; (void)out_size;

  // all weight transposes in one dispatch (all -> fp8 x16)
  transpose_all<<<14784, 256, 0, stream>>>(lm_w, dec_w1, dec_w2, proj_w, lm8, w18, w28, p8);

  // encoder on last token only (4-batch weight reuse)
  enc1p_kernel<<<dim3(HSZ / 256, KS1), 256, 0, stream>>>(input_ids, wte, enc_w1, t1p);
  enc2p_kernel<<<dim3(DSZ / 256, KS2), 256, 0, stream>>>(t1p, enc_b1, enc_w2, ep);
  enc2c_kernel<<<dim3(BSZ * DSZ / 256), 256, 0, stream>>>(ep, enc_b2, e);
  win8_kernel<<<2048, 256, 0, stream>>>(e, win8);

  // fp8 GEMM chain (1D grids, all divisible by 8 for the XCD swizzle)
  gemm8<0><<<128, 256, 0, stream>>>(win8, p8, proj_b, pbuf8, 8, DSZ, 512);
  gemm8<1><<<512, 256, 0, stream>>>(pbuf8, w18, dec_b1, abuf8, 32, HSZ, DSZ);
  gemm8<0><<<128, 256, 0, stream>>>(abuf8, w28, dec_b2, dbuf8, 8, DSZ, HSZ);
  // lm head MX-fp8: 394 m-tiles x 16 n-tiles = 6304 blocks
  gemmLM<<<6304, 256, 0, stream>>>(lm8, dbuf8, outF, pm, ps);

  // loss: two-stage merge + mean
  lsestage1_kernel<<<256, 256, 0, stream>>>(pm, ps, pm2, ps2);
  lsemerge_kernel<<<dim3(NPOS / 256), 256, 0, stream>>>(pm2, ps2, outF, labels, contrib);
  lossfinal_kernel<<<1, 256, 0, stream>>>(contrib, outF);
}